// Round 17
// baseline (633.235 us; speedup 1.0000x reference)
//
#include <hip/hip_runtime.h>
#include <hip/hip_bf16.h>

// Problem constants (fixed by setup_inputs).
#define BB 4
#define HH 96
#define WW 96
#define CC 512
#define NN 9216           // H*W
#define LL 141            // 64+36+25+16 pooled tokens
#define HID 2048
#define NHEAD 8
#define HD 64
#define NUNIT 564         // pool bin-chunks per image: 64*4+36*4+25*4+16*4

typedef __attribute__((ext_vector_type(8))) short bf16x8;
typedef __attribute__((ext_vector_type(4))) float f32x4;

// ---------- helpers ----------
__device__ __forceinline__ unsigned short f2bf(float f) {
  unsigned u = __float_as_uint(f);
  u = (u + 0x7fffu + ((u >> 16) & 1u)) >> 16;   // RNE
  return (unsigned short)u;
}
__device__ __forceinline__ float bf2f(unsigned short s) {
  return __uint_as_float((unsigned)s << 16);
}
__device__ __forceinline__ float bflo(unsigned u) { return __uint_as_float(u << 16); }
__device__ __forceinline__ float bfhi(unsigned u) { return __uint_as_float(u & 0xffff0000u); }
__device__ __forceinline__ unsigned packbf(float a, float b) {
  return (unsigned)f2bf(a) | ((unsigned)f2bf(b) << 16);
}
__device__ __forceinline__ float hswish(float x) {
  return x * fminf(fmaxf(x + 3.f, 0.f), 6.f) * (1.f / 6.f);
}
__device__ __forceinline__ void gld_lds16(const void* g, void* l) {
  __builtin_amdgcn_global_load_lds(
      (const __attribute__((address_space(1))) void*)g,
      (__attribute__((address_space(3))) void*)l, 16, 0, 0);
}

// ---------- f32 -> bf16 weight conversion ----------
__global__ __launch_bounds__(256) void w2bf(const float* __restrict__ in,
                                            unsigned short* __restrict__ out, int n4) {
  int i = blockIdx.x * 256 + threadIdx.x;
  if (i >= n4) return;
  float4 v = ((const float4*)in)[i];
  ushort4 o;
  o.x = f2bf(v.x); o.y = f2bf(v.y); o.z = f2bf(v.z); o.w = f2bf(v.w);
  ((ushort4*)out)[i] = o;
}

// ---------- conv_w [HID][9] -> wt [9][HID] ----------
__global__ __launch_bounds__(256) void wtrans(const float* __restrict__ w,
                                              float* __restrict__ wt) {
  int i = blockIdx.x * 256 + threadIdx.x;
  if (i >= 9 * HID) return;
  int k = i / HID, c = i - k * HID;
  wt[i] = w[c * 9 + k];
}

// ---------- LayerNorm over C=512, one block per row ----------
template <int OUTBF>
__global__ __launch_bounds__(256) void ln_kernel(const float* __restrict__ in,
                                                 const float* __restrict__ g,
                                                 const float* __restrict__ be,
                                                 void* __restrict__ outp) {
  int r = blockIdx.x;
  int t = threadIdx.x;
  const float* p = in + ((size_t)r << 9);
  float2 v = *(const float2*)(p + (t << 1));
  float s = v.x + v.y;
  float sq = v.x * v.x + v.y * v.y;
#pragma unroll
  for (int off = 32; off > 0; off >>= 1) {
    s += __shfl_down(s, off, 64);
    sq += __shfl_down(sq, off, 64);
  }
  __shared__ float red[8];
  int wid = t >> 6;
  if ((t & 63) == 0) { red[wid] = s; red[4 + wid] = sq; }
  __syncthreads();
  float ts = red[0] + red[1] + red[2] + red[3];
  float tq = red[4] + red[5] + red[6] + red[7];
  float mu = ts * (1.f / 512.f);
  float var = tq * (1.f / 512.f) - mu * mu;
  float inv = rsqrtf(var + 1e-5f);
  float2 gg = *(const float2*)(g + (t << 1));
  float2 bb = *(const float2*)(be + (t << 1));
  float ox = (v.x - mu) * inv * gg.x + bb.x;
  float oy = (v.y - mu) * inv * gg.y + bb.y;
  if constexpr (OUTBF) {
    ((unsigned*)outp)[((size_t)r << 8) + t] = packbf(ox, oy);
  } else {
    *(float2*)((float*)outp + ((size_t)r << 9) + (t << 1)) = make_float2(ox, oy);
  }
}

// ---------- MFMA GEMM: C = A[M,K](bf16) @ W[N,K](bf16)^T ----------
// 8-WAVE variant of the round-10 config: 512 threads, 128x128 tile, BK=64,
// double-buffered LDS (64 KB), 2-deep counted-vmcnt pipeline. Wave grid
// 2x4; each wave computes 64x32 (acc 4x2). Doubles waves/CU for latency
// hiding; staging is 4 loads/thread (vmcnt(4) keeps next tile in flight).
// Bank-conflict-free via source-side XOR swizzle (k-block b of row r holds
// global k-block b ^ (r&7); all row offsets are multiples of 8).
template <int EPI>
__global__ __launch_bounds__(512) void gemm_mfma(const unsigned short* __restrict__ A,
                                                 const unsigned short* __restrict__ W,
                                                 const float* __restrict__ bias,
                                                 const float* __restrict__ resid,
                                                 float* __restrict__ outF,
                                                 unsigned short* __restrict__ outB,
                                                 int M, int N, int K) {
  __shared__ __align__(16) unsigned short As[2][128 * 64];   // 2 x 16 KB
  __shared__ __align__(16) unsigned short Bs[2][128 * 64];   // 2 x 16 KB
  const int tid = threadIdx.x;
  const int w = tid >> 6;                 // 0..7
  const int l = tid & 63;
  const int m0 = blockIdx.x * 128;
  const int n0 = blockIdx.y * 128;
  const int wr = (w >> 2) << 6;           // 0 or 64
  const int wc = (w & 3) << 5;            // 0,32,64,96

  // staging: thread t -> row t>>3 (0..63) [+64 on 2nd load], k-block t&7,
  // source k pre-XORed so LDS k-block b of row r holds global block b^(r&7).
  const int srow = tid >> 3;
  const int skk = ((tid & 7) ^ (srow & 7)) << 3;
  const size_t a_row = (size_t)(m0 + srow) * K + skk;
  const size_t b_row = (size_t)(n0 + srow) * K + skk;
  const size_t rs = (size_t)64 * K;
  const int ld0 = w << 9;                 // wave slot (512 ushorts)

#define STAGE_G(d, k0)                                                      \
  {                                                                         \
    gld_lds16(A + a_row + (k0),      &As[d][ld0]);                          \
    gld_lds16(A + a_row + rs + (k0), &As[d][4096 + ld0]);                   \
    gld_lds16(W + b_row + (k0),      &Bs[d][ld0]);                          \
    gld_lds16(W + b_row + rs + (k0), &Bs[d][4096 + ld0]);                   \
  }

  f32x4 acc[4][2];
#pragma unroll
  for (int i = 0; i < 4; i++)
#pragma unroll
    for (int j = 0; j < 2; j++) acc[i][j] = (f32x4){0.f, 0.f, 0.f, 0.f};

  const int fr = l & 15;
  const int kb = l >> 4;                              // 0..3
  const int x0 = ((kb ^ (fr & 7)) << 3);              // swizzled read offsets
  const int x1 = (((kb + 4) ^ (fr & 7)) << 3);
  const int ar0 = (wr + fr) * 64;
  const int br0 = (wc + fr) * 64;
  const int br1 = (wc + 16 + fr) * 64;

  const int nt = K >> 6;
  STAGE_G(0, 0);
  STAGE_G(1, 64);

  int cur = 0;
  for (int t = 0; t < nt; ++t) {
    if (t + 1 < nt)
      asm volatile("s_waitcnt vmcnt(4)" ::: "memory");
    else
      asm volatile("s_waitcnt vmcnt(0)" ::: "memory");
    __builtin_amdgcn_s_barrier();

    bf16x8 a0[4], a1[4], b0[2], b1[2];
#pragma unroll
    for (int i = 0; i < 4; i++) {
      a0[i] = *(const bf16x8*)(&As[cur][ar0 + i * 1024 + x0]);
      a1[i] = *(const bf16x8*)(&As[cur][ar0 + i * 1024 + x1]);
    }
    b0[0] = *(const bf16x8*)(&Bs[cur][br0 + x0]);
    b1[0] = *(const bf16x8*)(&Bs[cur][br0 + x1]);
    b0[1] = *(const bf16x8*)(&Bs[cur][br1 + x0]);
    b1[1] = *(const bf16x8*)(&Bs[cur][br1 + x1]);
    asm volatile("s_waitcnt lgkmcnt(0)" ::: "memory");
    __builtin_amdgcn_s_barrier();          // all waves done reading buf[cur]
    if (t + 2 < nt) STAGE_G(cur, (size_t)(t + 2) << 6);

#pragma unroll
    for (int mi = 0; mi < 4; mi++)
#pragma unroll
      for (int ni = 0; ni < 2; ni++) {
        acc[mi][ni] = __builtin_amdgcn_mfma_f32_16x16x32_bf16(a0[mi], b0[ni],
                                                              acc[mi][ni], 0, 0, 0);
        acc[mi][ni] = __builtin_amdgcn_mfma_f32_16x16x32_bf16(a1[mi], b1[ni],
                                                              acc[mi][ni], 0, 0, 0);
      }
    cur ^= 1;
  }
#undef STAGE_G

  const int r4 = (l >> 4) << 2;
  float bval[2];
  if constexpr (EPI == 1 || EPI == 2) {
#pragma unroll
    for (int ni = 0; ni < 2; ni++) bval[ni] = bias[n0 + wc + ni * 16 + fr];
  }
#pragma unroll
  for (int mi = 0; mi < 4; mi++) {
#pragma unroll
    for (int j = 0; j < 4; j++) {
      const int gm = m0 + wr + mi * 16 + r4 + j;
#pragma unroll
      for (int ni = 0; ni < 2; ni++) {
        const int gn = n0 + wc + ni * 16 + fr;
        float v = acc[mi][ni][j];
        if constexpr (EPI == 1) {
          v += bval[ni] + resid[(size_t)gm * N + gn];
          outF[(size_t)gm * N + gn] = v;
        } else if constexpr (EPI == 2) {
          outB[(size_t)gm * N + gn] = f2bf(hswish(v + bval[ni]));
        } else if constexpr (EPI == 3) {
          outB[(size_t)gm * N + gn] = f2bf(v);
        } else {
          outF[(size_t)gm * N + gn] = v;
        }
      }
    }
  }
}

// ---------- small vector GEMM (kv only) ----------
template <typename AT, int EPI>
__global__ __launch_bounds__(256) void gemm_xwt(const AT* __restrict__ A,
                                                const float* __restrict__ Wt,
                                                const float* __restrict__ bias,
                                                const float* __restrict__ resid,
                                                float* __restrict__ outF,
                                                unsigned short* __restrict__ outB,
                                                int M, int N, int K) {
  __shared__ __align__(16) float As[16][68];
  __shared__ __align__(16) float Bs[16][68];
  int tid = threadIdx.x;
  int m0 = blockIdx.x * 64;
  int n0 = blockIdx.y * 64;
  int lr = tid >> 2;
  int lc = (tid & 3) << 2;
  int ty = tid >> 4, tx = tid & 15;
  float acc[4][4] = {};
  int grA = m0 + lr; if (grA > M - 1) grA = M - 1;
  const size_t arow = (size_t)grA * K + lc;
  const size_t brow = (size_t)(n0 + lr) * K + lc;

  for (int k0 = 0; k0 < K; k0 += 16) {
    float a0, a1, a2, a3;
    if constexpr (sizeof(AT) == 4) {
      float4 v = *reinterpret_cast<const float4*>(A + arow + k0);
      a0 = v.x; a1 = v.y; a2 = v.z; a3 = v.w;
    } else {
      ushort4 v = *reinterpret_cast<const ushort4*>(A + arow + k0);
      a0 = bf2f(v.x); a1 = bf2f(v.y); a2 = bf2f(v.z); a3 = bf2f(v.w);
    }
    float4 wv = *reinterpret_cast<const float4*>(Wt + brow + k0);
    As[lc + 0][lr] = a0; As[lc + 1][lr] = a1; As[lc + 2][lr] = a2; As[lc + 3][lr] = a3;
    Bs[lc + 0][lr] = wv.x; Bs[lc + 1][lr] = wv.y; Bs[lc + 2][lr] = wv.z; Bs[lc + 3][lr] = wv.w;
    __syncthreads();
#pragma unroll
    for (int kk = 0; kk < 16; kk++) {
      float4 av = *reinterpret_cast<const float4*>(&As[kk][ty << 2]);
      float4 bv = *reinterpret_cast<const float4*>(&Bs[kk][tx << 2]);
      acc[0][0] += av.x * bv.x; acc[0][1] += av.x * bv.y; acc[0][2] += av.x * bv.z; acc[0][3] += av.x * bv.w;
      acc[1][0] += av.y * bv.x; acc[1][1] += av.y * bv.y; acc[1][2] += av.y * bv.z; acc[1][3] += av.y * bv.w;
      acc[2][0] += av.z * bv.x; acc[2][1] += av.z * bv.y; acc[2][2] += av.z * bv.z; acc[2][3] += av.z * bv.w;
      acc[3][0] += av.w * bv.x; acc[3][1] += av.w * bv.y; acc[3][2] += av.w * bv.z; acc[3][3] += av.w * bv.w;
    }
    __syncthreads();
  }

  int gn0 = n0 + (tx << 2);
#pragma unroll
  for (int i = 0; i < 4; i++) {
    int gm = m0 + (ty << 2) + i;
    if (gm >= M) break;
    float4 v = make_float4(acc[i][0], acc[i][1], acc[i][2], acc[i][3]);
    if constexpr (EPI == 1) {
      float4 bb = *(const float4*)(bias + gn0);
      float4 rr = *(const float4*)(resid + (size_t)gm * N + gn0);
      v.x += bb.x + rr.x; v.y += bb.y + rr.y; v.z += bb.z + rr.z; v.w += bb.w + rr.w;
      *(float4*)(outF + (size_t)gm * N + gn0) = v;
    } else {
      *(float4*)(outF + (size_t)gm * N + gn0) = v;
    }
  }
}

// ---------- pooled-token index decode ----------
__device__ __forceinline__ void decode_l(int l, int& gi, int& ph, int& pw,
                                         int& oh, int& ow, int& base) {
  if (l < 64)       { gi = 0; base = 0;   oh = 8; ow = 8; }
  else if (l < 100) { gi = 1; base = 64;  oh = 6; ow = 6; }
  else if (l < 125) { gi = 2; base = 100; oh = 5; ow = 5; }
  else              { gi = 3; base = 125; oh = 4; ow = 4; }
  int loc = l - base;
  ph = loc / ow; pw = loc % ow;
}

// ---------- pooling stage A: per bin-row-chunk partial sums ----------
__global__ __launch_bounds__(256) void pool_partial(const unsigned short* __restrict__ xn,
                                                    float* __restrict__ partial) {
  const int gid = blockIdx.x;
  const int b = gid / NUNIT, u = gid % NUNIT;
  int ow_, cr, ubase;
  if (u < 256)      { ubase = 0;   ow_ = 8; cr = 3; }
  else if (u < 400) { ubase = 256; ow_ = 6; cr = 4; }
  else if (u < 500) { ubase = 400; ow_ = 5; cr = 5; }
  else              { ubase = 500; ow_ = 4; cr = 6; }
  const int v = u - ubase;
  const int bin = v >> 2, chunk = v & 3;
  const int ph = bin / ow_, pw = bin % ow_;
  const int sh = (ph * HH) / ow_;
  const int sw = (pw * WW) / ow_, ew = ((pw + 1) * WW + ow_ - 1) / ow_;
  const int y0 = sh + chunk * cr, y1 = y0 + cr;

  const int tid = threadIdx.x;
  const int cg = tid & 63, pl = tid >> 6;
  const unsigned short* xb = xn + (size_t)b * NN * CC + (cg << 3);

  float acc[8] = {0.f, 0.f, 0.f, 0.f, 0.f, 0.f, 0.f, 0.f};
  for (int y = y0; y < y1; y++) {
    const unsigned short* xr = xb + (size_t)(y * WW) * CC;
    for (int xx = sw + pl; xx < ew; xx += 4) {
      int4 vv = *(const int4*)(xr + (size_t)xx * CC);
      unsigned ua = (unsigned)vv.x, ub = (unsigned)vv.y,
               uc = (unsigned)vv.z, ud = (unsigned)vv.w;
      acc[0] += bflo(ua); acc[1] += bfhi(ua);
      acc[2] += bflo(ub); acc[3] += bfhi(ub);
      acc[4] += bflo(uc); acc[5] += bfhi(uc);
      acc[6] += bflo(ud); acc[7] += bfhi(ud);
    }
  }
  __shared__ float red[4][64][8];
#pragma unroll
  for (int j = 0; j < 8; j++) red[pl][cg][j] = acc[j];
  __syncthreads();
  if (tid < 64) {
    float s[8];
#pragma unroll
    for (int j = 0; j < 8; j++)
      s[j] = red[0][tid][j] + red[1][tid][j] + red[2][tid][j] + red[3][tid][j];
    float* dst = partial + (size_t)gid * CC + (tid << 3);
    *(float4*)dst = make_float4(s[0], s[1], s[2], s[3]);
    *(float4*)(dst + 4) = make_float4(s[4], s[5], s[6], s[7]);
  }
}

// ---------- pooling stage B: sum 4 chunk-partials, apply 1/area ----------
__global__ __launch_bounds__(256) void pool_reduce(const float* __restrict__ partial,
                                                   float* __restrict__ pr) {
  const int bl = blockIdx.x;
  const int b = bl / LL, l = bl % LL;
  int gi, ph, pw, oh, ow, base; decode_l(l, gi, ph, pw, oh, ow, base);
  const int sh = (ph * HH) / oh, eh = ((ph + 1) * HH + oh - 1) / oh;
  const int sw = (pw * WW) / ow, ew = ((pw + 1) * WW + ow - 1) / ow;
  const float inv_area = 1.f / (float)((eh - sh) * (ew - sw));
  int u0;
  if (l < 64)       u0 = l * 4;
  else if (l < 100) u0 = 256 + (l - 64) * 4;
  else if (l < 125) u0 = 400 + (l - 100) * 4;
  else              u0 = 500 + (l - 125) * 4;
  const float* p0 = partial + ((size_t)(b * NUNIT + u0)) * CC;
  const int c = threadIdx.x << 1;
  float2 a0 = *(const float2*)(p0 + c);
  float2 a1 = *(const float2*)(p0 + CC + c);
  float2 a2 = *(const float2*)(p0 + 2 * CC + c);
  float2 a3 = *(const float2*)(p0 + 3 * CC + c);
  float2 r;
  r.x = (a0.x + a1.x + a2.x + a3.x) * inv_area;
  r.y = (a0.y + a1.y + a2.y + a3.y) * inv_area;
  *(float2*)(pr + ((size_t)(b * LL + l)) * CC + c) = r;
}

// ---------- pool += dwconv3x3(pool) + bias ----------
__global__ __launch_bounds__(256) void pool_dwconv(const float* __restrict__ pin,
                                                   const float* __restrict__ dw,
                                                   const float* __restrict__ db,
                                                   float* __restrict__ pout) {
  int bl = blockIdx.x;
  int b = bl / LL, l = bl % LL;
  int gi, ph, pw, oh, ow, base; decode_l(l, gi, ph, pw, oh, ow, base);
  for (int c = threadIdx.x; c < CC; c += 256) {
    float acc = db[gi * CC + c];
#pragma unroll
    for (int dy = -1; dy <= 1; dy++) {
      int y = ph + dy; if ((unsigned)y >= (unsigned)oh) continue;
#pragma unroll
      for (int dx = -1; dx <= 1; dx++) {
        int x = pw + dx; if ((unsigned)x >= (unsigned)ow) continue;
        acc += dw[((size_t)(gi * CC + c)) * 9 + (dy + 1) * 3 + (dx + 1)] *
               pin[((size_t)(b * LL) + base + y * ow + x) * CC + c];
      }
    }
    pout[((size_t)(b * LL + l)) * CC + c] =
        pin[((size_t)(b * LL + l)) * CC + c] + acc;
  }
}

// ---------- kv prep: f32 kv -> pre-swizzled bf16 K and V^T per (b,h) ----------
__global__ __launch_bounds__(256) void kvprep(const float* __restrict__ kvb,
                                              unsigned short* __restrict__ kpack,
                                              unsigned short* __restrict__ vtpack) {
  const int bh = blockIdx.x;
  const int b = bh >> 3, h = bh & 7;
  unsigned short* kd = kpack + (size_t)bh * 10240;
  unsigned short* vd = vtpack + (size_t)bh * 12288;
  for (int idx = threadIdx.x; idx < 1280; idx += 256) {
    const int row = idx >> 3, blk = idx & 7;
    int4 pk = make_int4(0, 0, 0, 0);
    if (row < LL) {
      const float* kp = kvb + ((size_t)(b * LL + row) << 10) + (h << 6) + (blk << 3);
      float4 v0 = *(const float4*)kp;
      float4 v1 = *(const float4*)(kp + 4);
      pk.x = (int)packbf(v0.x, v0.y); pk.y = (int)packbf(v0.z, v0.w);
      pk.z = (int)packbf(v1.x, v1.y); pk.w = (int)packbf(v1.z, v1.w);
    }
    *(int4*)(kd + row * 64 + ((blk ^ (row & 7)) << 3)) = pk;
    const int l = row, d0 = blk << 3, lb = l >> 3;
    unsigned short vv[8] = {0, 0, 0, 0, 0, 0, 0, 0};
    if (l < LL) {
      const float* vp = kvb + ((size_t)(b * LL + l) << 10) + 512 + (h << 6) + d0;
      float4 v0 = *(const float4*)vp;
      float4 v1 = *(const float4*)(vp + 4);
      vv[0] = f2bf(v0.x); vv[1] = f2bf(v0.y); vv[2] = f2bf(v0.z); vv[3] = f2bf(v0.w);
      vv[4] = f2bf(v1.x); vv[5] = f2bf(v1.y); vv[6] = f2bf(v1.z); vv[7] = f2bf(v1.w);
    }
#pragma unroll
    for (int j = 0; j < 8; j++) {
      const int d = d0 + j;
      vd[d * 192 + ((lb ^ (d & 7)) << 3) + (l & 7)] = vv[j];
    }
  }
}

// ---------- MFMA fused attention (pure gld_lds staging from pre-swizzled kv) ----------
__global__ __launch_bounds__(256) void attn_mfma(const unsigned short* __restrict__ q,
                                                 const unsigned short* __restrict__ kpack,
                                                 const unsigned short* __restrict__ vtpack,
                                                 unsigned short* __restrict__ out) {
  __shared__ __align__(16) unsigned short Ks[160 * 64];
  __shared__ __align__(16) unsigned short Vt[64 * 192];
  __shared__ __align__(16) unsigned short Pl[4 * 16 * 192];
  const int bh = blockIdx.x;
  const int b = bh >> 3;
  const int tid = threadIdx.x;
  const int w = tid >> 6, lane = tid & 63;

  const unsigned short* kg = kpack + (size_t)bh * 10240;
  const unsigned short* vg = vtpack + (size_t)bh * 12288;
#pragma unroll
  for (int p = 0; p < 5; p++)
    gld_lds16(kg + (p << 11) + (tid << 3), Ks + (p << 11) + (w << 9));
#pragma unroll
  for (int p = 0; p < 6; p++)
    gld_lds16(vg + (p << 11) + (tid << 3), Vt + (p << 11) + (w << 9));

  const int qrow = blockIdx.y * 64 + w * 16 + (lane & 15);
  const unsigned short* qp = q + ((size_t)(b * NN + qrow) << 9) + ((bh & 7) << 6) + ((lane >> 4) << 3);
  bf16x8 qf0 = *(const bf16x8*)qp;
  bf16x8 qf1 = *(const bf16x8*)(qp + 32);

  __syncthreads();

  f32x4 s[9];
  const int kb = lane >> 4;
  const int mycol = lane & 15;
#pragma unroll
  for (int lt = 0; lt < 9; lt++) {
    int lcol = lt * 16 + mycol;
    const unsigned short* kr = Ks + lcol * 64;
    bf16x8 k0 = *(const bf16x8*)(kr + ((kb ^ (lcol & 7)) << 3));
    bf16x8 k1 = *(const bf16x8*)(kr + (((kb + 4) ^ (lcol & 7)) << 3));
    f32x4 a = (f32x4){0.f, 0.f, 0.f, 0.f};
    a = __builtin_amdgcn_mfma_f32_16x16x32_bf16(qf0, k0, a, 0, 0, 0);
    a = __builtin_amdgcn_mfma_f32_16x16x32_bf16(qf1, k1, a, 0, 0, 0);
    s[lt] = a;
  }
#pragma unroll
  for (int lt = 0; lt < 9; lt++) {
#pragma unroll
    for (int j = 0; j < 4; j++) {
      float v = s[lt][j] * 0.125f;
      if (lt == 8 && mycol >= 13) v = -1e30f;
      s[lt][j] = v;
    }
  }
  float sm[4];
#pragma unroll
  for (int j = 0; j < 4; j++) {
    float m = s[0][j];
#pragma unroll
    for (int lt = 1; lt < 9; lt++) m = fmaxf(m, s[lt][j]);
#pragma unroll
    for (int off = 1; off < 16; off <<= 1) m = fmaxf(m, __shfl_xor(m, off, 64));
    float su = 0.f;
#pragma unroll
    for (int lt = 0; lt < 9; lt++) {
      float p = __expf(s[lt][j] - m);
      s[lt][j] = p;
      su += p;
    }
#pragma unroll
    for (int off = 1; off < 16; off <<= 1) su += __shfl_xor(su, off, 64);
    sm[j] = su;
  }

  unsigned short* Pw = Pl + w * (16 * 192);
#pragma unroll
  for (int lt = 0; lt < 9; lt++) {
#pragma unroll
    for (int j = 0; j < 4; j++) {
      int qr_ = (lane >> 4) * 4 + j;
      int lcol = lt * 16 + mycol;
      Pw[qr_ * 192 + (((lcol >> 3) ^ (qr_ & 7)) << 3) + (lcol & 7)] = f2bf(s[lt][j]);
    }
  }
#pragma unroll
  for (int j = 0; j < 4; j++) {
    int qr_ = mycol;
    int lcol = 144 + (lane >> 4) * 4 + j;
    Pw[qr_ * 192 + (((lcol >> 3) ^ (qr_ & 7)) << 3) + (lcol & 7)] = 0;
  }
  __syncthreads();

  f32x4 o[4];
#pragma unroll
  for (int dt = 0; dt < 4; dt++) o[dt] = (f32x4){0.f, 0.f, 0.f, 0.f};
#pragma unroll
  for (int lc = 0; lc < 5; lc++) {
    int lb = lc * 4 + (lane >> 4);
    bf16x8 pa = *(const bf16x8*)(Pw + mycol * 192 + ((lb ^ (mycol & 7)) << 3));
#pragma unroll
    for (int dt = 0; dt < 4; dt++) {
      int d = dt * 16 + mycol;
      bf16x8 vb = *(const bf16x8*)(Vt + d * 192 + ((lb ^ (d & 7)) << 3));
      o[dt] = __builtin_amdgcn_mfma_f32_16x16x32_bf16(pa, vb, o[dt], 0, 0, 0);
    }
  }

  float inv[4];
#pragma unroll
  for (int j = 0; j < 4; j++) inv[j] = 1.f / sm[j];
#pragma unroll
  for (int dt = 0; dt < 4; dt++) {
#pragma unroll
    for (int j = 0; j < 4; j++) {
      int qg = blockIdx.y * 64 + w * 16 + (lane >> 4) * 4 + j;
      out[((size_t)(b * NN + qg) << 9) + ((bh & 7) << 6) + dt * 16 + mycol] =
          f2bf(o[dt][j] * inv[j]);
    }
  }
}

// ---------- depthwise 3x3 sliding-window; grid (384, n_images) ----------
__device__ __forceinline__ void dw_ldcol(const unsigned short* __restrict__ img,
                                         int hh, int xx, int o0, float* __restrict__ f) {
  const bool xok = (unsigned)xx < (unsigned)WW;
#pragma unroll
  for (int r = 0; r < 3; r++) {
    const int y = hh - 1 + r;
    int4 v = make_int4(0, 0, 0, 0);
    if (xok && (unsigned)y < (unsigned)HH)
      v = *(const int4*)(img + ((size_t)(y * WW + xx) * HID) + o0);
    unsigned ua = (unsigned)v.x, ub = (unsigned)v.y,
             uc = (unsigned)v.z, ud = (unsigned)v.w;
    f[r * 8 + 0] = bflo(ua); f[r * 8 + 1] = bfhi(ua);
    f[r * 8 + 2] = bflo(ub); f[r * 8 + 3] = bfhi(ub);
    f[r * 8 + 4] = bflo(uc); f[r * 8 + 5] = bfhi(uc);
    f[r * 8 + 6] = bflo(ud); f[r * 8 + 7] = bfhi(ud);
  }
}

__device__ __forceinline__ void dw_emit(const float wr[9][8], const float bs[8],
                                        const float* __restrict__ A,
                                        const float* __restrict__ B,
                                        const float* __restrict__ C,
                                        unsigned short* __restrict__ t2,
                                        int hh, int xx, int o0) {
  float acc[8];
#pragma unroll
  for (int j = 0; j < 8; j++) acc[j] = bs[j];
#pragma unroll
  for (int r = 0; r < 3; r++) {
#pragma unroll
    for (int j = 0; j < 8; j++) {
      acc[j] += wr[r * 3 + 0][j] * A[r * 8 + j];
      acc[j] += wr[r * 3 + 1][j] * B[r * 8 + j];
      acc[j] += wr[r * 3 + 2][j] * C[r * 8 + j];
    }
  }
  int4 o;
  o.x = (int)packbf(hswish(acc[0]), hswish(acc[1]));
  o.y = (int)packbf(hswish(acc[2]), hswish(acc[3]));
  o.z = (int)packbf(hswish(acc[4]), hswish(acc[5]));
  o.w = (int)packbf(hswish(acc[6]), hswish(acc[7]));
  *(int4*)(t2 + ((size_t)(hh * WW + xx) * HID) + o0) = o;
}

__global__ __launch_bounds__(256) void dwconv_hid(const unsigned short* __restrict__ t1,
                                                  const float* __restrict__ wt,
                                                  const float* __restrict__ bias,
                                                  unsigned short* __restrict__ t2) {
  const int bx = blockIdx.x;            // 0..383
  const size_t ioff = (size_t)blockIdx.y * NN * HID;
  const unsigned short* t1i = t1 + ioff;
  unsigned short* t2i = t2 + ioff;
  const int hh = bx >> 2, quarter = bx & 3;
  const int x0 = quarter * 24;
  const int o0 = threadIdx.x << 3;

  float wr[9][8];
#pragma unroll
  for (int k = 0; k < 9; k++) {
    float4 w0 = *(const float4*)(wt + k * HID + o0);
    float4 w1 = *(const float4*)(wt + k * HID + o0 + 4);
    wr[k][0] = w0.x; wr[k][1] = w0.y; wr[k][2] = w0.z; wr[k][3] = w0.w;
    wr[k][4] = w1.x; wr[k][5] = w1.y; wr[k][6] = w1.z; wr[k][7] = w1.w;
  }
  float bs[8];
  {
    float4 b0 = *(const float4*)(bias + o0);
    float4 b1 = *(const float4*)(bias + o0 + 4);
    bs[0] = b0.x; bs[1] = b0.y; bs[2] = b0.z; bs[3] = b0.w;
    bs[4] = b1.x; bs[5] = b1.y; bs[6] = b1.z; bs[7] = b1.w;
  }

  float cm[24], cc[24], cn[24];
  dw_ldcol(t1i, hh, x0 - 1, o0, cm);
  dw_ldcol(t1i, hh, x0, o0, cc);
  for (int xx = x0; xx < x0 + 24; xx += 3) {
    dw_ldcol(t1i, hh, xx + 1, o0, cn);
    dw_emit(wr, bs, cm, cc, cn, t2i, hh, xx, o0);
    dw_ldcol(t1i, hh, xx + 2, o0, cm);
    dw_emit(wr, bs, cc, cn, cm, t2i, hh, xx + 1, o0);
    dw_ldcol(t1i, hh, xx + 3, o0, cc);
    dw_emit(wr, bs, cn, cm, cc, t2i, hh, xx + 2, o0);
  }
}

// ---------- launch ----------
extern "C" void kernel_launch(void* const* d_in, const int* in_sizes, int n_in,
                              void* d_out, int out_size, void* d_ws, size_t ws_size,
                              hipStream_t stream) {
  const float* x        = (const float*)d_in[0];
  const float* norm1_g  = (const float*)d_in[1];
  const float* norm1_b  = (const float*)d_in[2];
  const float* q_w      = (const float*)d_in[3];
  const float* kv_w     = (const float*)d_in[4];
  const float* anorm_g  = (const float*)d_in[5];
  const float* anorm_b  = (const float*)d_in[6];
  const float* proj_w   = (const float*)d_in[7];
  const float* proj_b   = (const float*)d_in[8];
  const float* dconv_w  = (const float*)d_in[9];
  const float* dconv_b  = (const float*)d_in[10];
  const float* norm2_g  = (const float*)d_in[11];
  const float* norm2_b  = (const float*)d_in[12];
  const float* fc1_w    = (const float*)d_in[13];
  const float* fc1_b    = (const float*)d_in[14];
  const float* conv_w   = (const float*)d_in[15];
  const float* conv_b   = (const float*)d_in[16];
  const float* fc2_w    = (const float*)d_in[17];
  const float* fc2_b    = (const float*)d_in[18];
  float* out = (float*)d_out;

  char* ws = (char*)d_ws;
  const size_t SZ_BIG = (size_t)BB * NN * CC * 2;          // 37,748,736
  unsigned short* bufA = (unsigned short*)(ws);
  unsigned short* bufB = (unsigned short*)(ws + SZ_BIG);
  unsigned short* bufC = (unsigned short*)(ws + 2 * SZ_BIG);
  // weights (persistent through launch)
  char* wbase = ws + 3 * SZ_BIG;
  unsigned short* qw16   = (unsigned short*)(wbase);                  // 524288 B
  unsigned short* pw16   = (unsigned short*)(wbase + 524288);         // 524288 B
  unsigned short* fc1w16 = (unsigned short*)(wbase + 1048576);        // 2097152 B
  unsigned short* fc2w16 = (unsigned short*)(wbase + 3145728);        // 2097152 B
  float* wt              = (float*)(wbase + 5242880);                 // 73728 B
  // kvb (dead after kvprep)
  float* kvb = (float*)(wbase + 5316608);                             // 2310144 B
  // scratch (phase-overlapped)
  char* sb = wbase + 7626752;
  float* pools_raw = (float*)(sb);                                    // 1155072 B
  float* pools_c   = (float*)(sb + 1155072);
  float* pools_n   = (float*)(sb + 2 * 1155072);
  float* pool_part = (float*)(sb + 3 * 1155072);                      // 4620288 B
  // kpack/vtpack written after pools are dead
  unsigned short* kpack  = (unsigned short*)(sb);                     // 655360 B
  unsigned short* vtpack = (unsigned short*)(sb + 655360);            // 786432 B
  // batched-IRB t2 (written after kvb/pools/kpack all dead)
  unsigned short* t2b = (unsigned short*)(wbase + 5316608);           // 75497472 B
  const size_t need_batched =
      3 * SZ_BIG + 5316608ull + (size_t)2 * NN * HID * 2;             // 194,060,288
  const bool batched = ws_size >= need_batched;

  const int ROWS = BB * NN;   // 36864

  w2bf<<<(262144 / 4 + 255) / 256, 256, 0, stream>>>(q_w, qw16, 262144 / 4);
  w2bf<<<(262144 / 4 + 255) / 256, 256, 0, stream>>>(proj_w, pw16, 262144 / 4);
  w2bf<<<(1048576 / 4 + 255) / 256, 256, 0, stream>>>(fc1_w, fc1w16, 1048576 / 4);
  w2bf<<<(1048576 / 4 + 255) / 256, 256, 0, stream>>>(fc2_w, fc2w16, 1048576 / 4);
  wtrans<<<(9 * HID + 255) / 256, 256, 0, stream>>>(conv_w, wt);

  ln_kernel<1><<<ROWS, 256, 0, stream>>>(x, norm1_g, norm1_b, bufA);
  gemm_mfma<3><<<dim3(ROWS / 128, CC / 128), 512, 0, stream>>>(
      bufA, qw16, nullptr, nullptr, nullptr, bufB, ROWS, CC, CC);
  pool_partial<<<BB * NUNIT, 256, 0, stream>>>(bufA, pool_part);
  pool_reduce<<<BB * LL, 256, 0, stream>>>(pool_part, pools_raw);
  pool_dwconv<<<BB * LL, 256, 0, stream>>>(pools_raw, dconv_w, dconv_b, pools_c);
  ln_kernel<0><<<BB * LL, 256, 0, stream>>>(pools_c, anorm_g, anorm_b, pools_n);
  gemm_xwt<float, 0><<<dim3((BB * LL + 63) / 64, (2 * CC) / 64), 256, 0, stream>>>(
      pools_n, kv_w, nullptr, nullptr, kvb, nullptr, BB * LL, 2 * CC, CC);
  kvprep<<<BB * NHEAD, 256, 0, stream>>>(kvb, kpack, vtpack);
  attn_mfma<<<dim3(BB * NHEAD, NN / 64), 256, 0, stream>>>(bufB, kpack, vtpack, bufC);
  gemm_mfma<1><<<dim3(ROWS / 128, CC / 128), 512, 0, stream>>>(
      bufC, pw16, proj_b, x, out, nullptr, ROWS, CC, CC);
  ln_kernel<1><<<ROWS, 256, 0, stream>>>(out, norm2_g, norm2_b, bufC);

  if (batched) {
    for (int g = 0; g < 2; g++) {
      const unsigned short* xn2g = bufC + (size_t)g * 2 * NN * CC;
      float* outg = out + (size_t)g * 2 * NN * CC;
      gemm_mfma<2><<<dim3(2 * NN / 128, HID / 128), 512, 0, stream>>>(
          xn2g, fc1w16, fc1_b, nullptr, nullptr, bufA, 2 * NN, HID, CC);
      dwconv_hid<<<dim3(384, 2), 256, 0, stream>>>(bufA, wt, conv_b, t2b);
      gemm_mfma<1><<<dim3(2 * NN / 128, CC / 128), 512, 0, stream>>>(
          t2b, fc2w16, fc2_b, outg, outg, nullptr, 2 * NN, CC, HID);
    }
  } else {
    for (int b = 0; b < BB; b++) {
      const unsigned short* xn2b = bufC + (size_t)b * NN * CC;
      gemm_mfma<2><<<dim3(NN / 128, HID / 128), 512, 0, stream>>>(
          xn2b, fc1w16, fc1_b, nullptr, nullptr, bufA, NN, HID, CC);
      dwconv_hid<<<dim3(384, 1), 256, 0, stream>>>(bufA, wt, conv_b, bufB);
      gemm_mfma<1><<<dim3(NN / 128, CC / 128), 512, 0, stream>>>(
          bufB, fc2w16, fc2_b, out + (size_t)b * NN * CC, out + (size_t)b * NN * CC,
          nullptr, NN, CC, HID);
    }
  }
}

// Round 18
// 626.241 us; speedup vs baseline: 1.0112x; 1.0112x over previous
//
#include <hip/hip_runtime.h>
#include <hip/hip_bf16.h>

// Problem constants (fixed by setup_inputs).
#define BB 4
#define HH 96
#define WW 96
#define CC 512
#define NN 9216           // H*W
#define LL 141            // 64+36+25+16 pooled tokens
#define HID 2048
#define NHEAD 8
#define HD 64
#define NUNIT 564         // pool bin-chunks per image: 64*4+36*4+25*4+16*4

typedef __attribute__((ext_vector_type(8))) short bf16x8;
typedef __attribute__((ext_vector_type(4))) float f32x4;

// ---------- helpers ----------
__device__ __forceinline__ unsigned short f2bf(float f) {
  unsigned u = __float_as_uint(f);
  u = (u + 0x7fffu + ((u >> 16) & 1u)) >> 16;   // RNE
  return (unsigned short)u;
}
__device__ __forceinline__ float bf2f(unsigned short s) {
  return __uint_as_float((unsigned)s << 16);
}
__device__ __forceinline__ float bflo(unsigned u) { return __uint_as_float(u << 16); }
__device__ __forceinline__ float bfhi(unsigned u) { return __uint_as_float(u & 0xffff0000u); }
__device__ __forceinline__ unsigned packbf(float a, float b) {
  return (unsigned)f2bf(a) | ((unsigned)f2bf(b) << 16);
}
__device__ __forceinline__ float hswish(float x) {
  return x * fminf(fmaxf(x + 3.f, 0.f), 6.f) * (1.f / 6.f);
}
__device__ __forceinline__ void gld_lds16(const void* g, void* l) {
  __builtin_amdgcn_global_load_lds(
      (const __attribute__((address_space(1))) void*)g,
      (__attribute__((address_space(3))) void*)l, 16, 0, 0);
}

// ---------- f32 -> bf16 weight conversion ----------
__global__ __launch_bounds__(256) void w2bf(const float* __restrict__ in,
                                            unsigned short* __restrict__ out, int n4) {
  int i = blockIdx.x * 256 + threadIdx.x;
  if (i >= n4) return;
  float4 v = ((const float4*)in)[i];
  ushort4 o;
  o.x = f2bf(v.x); o.y = f2bf(v.y); o.z = f2bf(v.z); o.w = f2bf(v.w);
  ((ushort4*)out)[i] = o;
}

// ---------- conv_w [HID][9] -> wt [9][HID] ----------
__global__ __launch_bounds__(256) void wtrans(const float* __restrict__ w,
                                              float* __restrict__ wt) {
  int i = blockIdx.x * 256 + threadIdx.x;
  if (i >= 9 * HID) return;
  int k = i / HID, c = i - k * HID;
  wt[i] = w[c * 9 + k];
}

// ---------- LayerNorm over C=512, one block per row ----------
template <int OUTBF>
__global__ __launch_bounds__(256) void ln_kernel(const float* __restrict__ in,
                                                 const float* __restrict__ g,
                                                 const float* __restrict__ be,
                                                 void* __restrict__ outp) {
  int r = blockIdx.x;
  int t = threadIdx.x;
  const float* p = in + ((size_t)r << 9);
  float2 v = *(const float2*)(p + (t << 1));
  float s = v.x + v.y;
  float sq = v.x * v.x + v.y * v.y;
#pragma unroll
  for (int off = 32; off > 0; off >>= 1) {
    s += __shfl_down(s, off, 64);
    sq += __shfl_down(sq, off, 64);
  }
  __shared__ float red[8];
  int wid = t >> 6;
  if ((t & 63) == 0) { red[wid] = s; red[4 + wid] = sq; }
  __syncthreads();
  float ts = red[0] + red[1] + red[2] + red[3];
  float tq = red[4] + red[5] + red[6] + red[7];
  float mu = ts * (1.f / 512.f);
  float var = tq * (1.f / 512.f) - mu * mu;
  float inv = rsqrtf(var + 1e-5f);
  float2 gg = *(const float2*)(g + (t << 1));
  float2 bb = *(const float2*)(be + (t << 1));
  float ox = (v.x - mu) * inv * gg.x + bb.x;
  float oy = (v.y - mu) * inv * gg.y + bb.y;
  if constexpr (OUTBF) {
    ((unsigned*)outp)[((size_t)r << 8) + t] = packbf(ox, oy);
  } else {
    *(float2*)((float*)outp + ((size_t)r << 9) + (t << 1)) = make_float2(ox, oy);
  }
}

// ---------- MFMA GEMM: C = A[M,K](bf16) @ W[N,K](bf16)^T ----------
// BEST MEASURED CONFIG (round 10/16): BK=64, double-buffered LDS (64 KB),
// 2-deep counted-vmcnt pipeline: prologue stages tiles 0,1; iter t waits
// vmcnt(8) (tile t+1 stays in flight across the barrier), ds_reads frags,
// lgkmcnt(0)+barrier, STAGE(t+2) into the just-read buffer, 32 MFMA.
// vmcnt(0) only on final iter. Bank-conflict-free via source-side XOR
// swizzle (LDS k-block b of row r holds global k-block b ^ (r&7)).
template <int EPI>
__global__ __launch_bounds__(256) void gemm_mfma(const unsigned short* __restrict__ A,
                                                 const unsigned short* __restrict__ W,
                                                 const float* __restrict__ bias,
                                                 const float* __restrict__ resid,
                                                 float* __restrict__ outF,
                                                 unsigned short* __restrict__ outB,
                                                 int M, int N, int K) {
  __shared__ __align__(16) unsigned short As[2][128 * 64];   // 2 x 16 KB
  __shared__ __align__(16) unsigned short Bs[2][128 * 64];   // 2 x 16 KB
  const int tid = threadIdx.x;
  const int w = tid >> 6;
  const int l = tid & 63;
  const int m0 = blockIdx.x * 128;
  const int n0 = blockIdx.y * 128;
  const int wr = (w >> 1) << 6;
  const int wc = (w & 1) << 6;

  const int srow = tid >> 3;                         // 0..31
  const int skk = ((tid & 7) ^ (srow & 7)) << 3;     // pre-swizzled k elem offset
  const size_t a_row = (size_t)(m0 + srow) * K + skk;
  const size_t b_row = (size_t)(n0 + srow) * K + skk;
  const size_t rs = (size_t)32 * K;
  const int ld0 = w << 9;                            // wave slot (512 ushorts)

#define STAGE_G(d, k0)                                                      \
  {                                                                         \
    gld_lds16(A + a_row + (k0),          &As[d][ld0]);                      \
    gld_lds16(A + a_row + rs + (k0),     &As[d][2048 + ld0]);               \
    gld_lds16(A + a_row + 2 * rs + (k0), &As[d][4096 + ld0]);               \
    gld_lds16(A + a_row + 3 * rs + (k0), &As[d][6144 + ld0]);               \
    gld_lds16(W + b_row + (k0),          &Bs[d][ld0]);                      \
    gld_lds16(W + b_row + rs + (k0),     &Bs[d][2048 + ld0]);               \
    gld_lds16(W + b_row + 2 * rs + (k0), &Bs[d][4096 + ld0]);               \
    gld_lds16(W + b_row + 3 * rs + (k0), &Bs[d][6144 + ld0]);               \
  }

  f32x4 acc[4][4];
#pragma unroll
  for (int i = 0; i < 4; i++)
#pragma unroll
    for (int j = 0; j < 4; j++) acc[i][j] = (f32x4){0.f, 0.f, 0.f, 0.f};

  const int fr = l & 15;
  const int kb = l >> 4;                              // 0..3
  const int x0 = ((kb ^ (fr & 7)) << 3);              // swizzled read offsets
  const int x1 = (((kb + 4) ^ (fr & 7)) << 3);
  const int ar0 = (wr + fr) * 64;
  const int br0 = (wc + fr) * 64;

  const int nt = K >> 6;                              // >= 2 for all our shapes
  STAGE_G(0, 0);
  STAGE_G(1, 64);

  int cur = 0;
  for (int t = 0; t < nt; ++t) {
    if (t + 1 < nt)
      asm volatile("s_waitcnt vmcnt(8)" ::: "memory");
    else
      asm volatile("s_waitcnt vmcnt(0)" ::: "memory");
    __builtin_amdgcn_s_barrier();

    bf16x8 a0[4], a1[4], b0[4], b1[4];
#pragma unroll
    for (int i = 0; i < 4; i++) {
      a0[i] = *(const bf16x8*)(&As[cur][ar0 + i * 1024 + x0]);
      a1[i] = *(const bf16x8*)(&As[cur][ar0 + i * 1024 + x1]);
      b0[i] = *(const bf16x8*)(&Bs[cur][br0 + i * 1024 + x0]);
      b1[i] = *(const bf16x8*)(&Bs[cur][br0 + i * 1024 + x1]);
    }
    asm volatile("s_waitcnt lgkmcnt(0)" ::: "memory");
    __builtin_amdgcn_s_barrier();          // all waves done reading buf[cur]
    if (t + 2 < nt) STAGE_G(cur, (size_t)(t + 2) << 6);

#pragma unroll
    for (int mi = 0; mi < 4; mi++)
#pragma unroll
      for (int ni = 0; ni < 4; ni++) {
        acc[mi][ni] = __builtin_amdgcn_mfma_f32_16x16x32_bf16(a0[mi], b0[ni],
                                                              acc[mi][ni], 0, 0, 0);
        acc[mi][ni] = __builtin_amdgcn_mfma_f32_16x16x32_bf16(a1[mi], b1[ni],
                                                              acc[mi][ni], 0, 0, 0);
      }
    cur ^= 1;
  }
#undef STAGE_G

  const int r4 = (l >> 4) << 2;
  float bval[4];
  if constexpr (EPI == 1 || EPI == 2) {
#pragma unroll
    for (int ni = 0; ni < 4; ni++) bval[ni] = bias[n0 + wc + ni * 16 + fr];
  }
#pragma unroll
  for (int mi = 0; mi < 4; mi++) {
#pragma unroll
    for (int j = 0; j < 4; j++) {
      const int gm = m0 + wr + mi * 16 + r4 + j;
#pragma unroll
      for (int ni = 0; ni < 4; ni++) {
        const int gn = n0 + wc + ni * 16 + fr;
        float v = acc[mi][ni][j];
        if constexpr (EPI == 1) {
          v += bval[ni] + resid[(size_t)gm * N + gn];
          outF[(size_t)gm * N + gn] = v;
        } else if constexpr (EPI == 2) {
          outB[(size_t)gm * N + gn] = f2bf(hswish(v + bval[ni]));
        } else if constexpr (EPI == 3) {
          outB[(size_t)gm * N + gn] = f2bf(v);
        } else {
          outF[(size_t)gm * N + gn] = v;
        }
      }
    }
  }
}

// ---------- small vector GEMM (kv only) ----------
template <typename AT, int EPI>
__global__ __launch_bounds__(256) void gemm_xwt(const AT* __restrict__ A,
                                                const float* __restrict__ Wt,
                                                const float* __restrict__ bias,
                                                const float* __restrict__ resid,
                                                float* __restrict__ outF,
                                                unsigned short* __restrict__ outB,
                                                int M, int N, int K) {
  __shared__ __align__(16) float As[16][68];
  __shared__ __align__(16) float Bs[16][68];
  int tid = threadIdx.x;
  int m0 = blockIdx.x * 64;
  int n0 = blockIdx.y * 64;
  int lr = tid >> 2;
  int lc = (tid & 3) << 2;
  int ty = tid >> 4, tx = tid & 15;
  float acc[4][4] = {};
  int grA = m0 + lr; if (grA > M - 1) grA = M - 1;
  const size_t arow = (size_t)grA * K + lc;
  const size_t brow = (size_t)(n0 + lr) * K + lc;

  for (int k0 = 0; k0 < K; k0 += 16) {
    float a0, a1, a2, a3;
    if constexpr (sizeof(AT) == 4) {
      float4 v = *reinterpret_cast<const float4*>(A + arow + k0);
      a0 = v.x; a1 = v.y; a2 = v.z; a3 = v.w;
    } else {
      ushort4 v = *reinterpret_cast<const ushort4*>(A + arow + k0);
      a0 = bf2f(v.x); a1 = bf2f(v.y); a2 = bf2f(v.z); a3 = bf2f(v.w);
    }
    float4 wv = *reinterpret_cast<const float4*>(Wt + brow + k0);
    As[lc + 0][lr] = a0; As[lc + 1][lr] = a1; As[lc + 2][lr] = a2; As[lc + 3][lr] = a3;
    Bs[lc + 0][lr] = wv.x; Bs[lc + 1][lr] = wv.y; Bs[lc + 2][lr] = wv.z; Bs[lc + 3][lr] = wv.w;
    __syncthreads();
#pragma unroll
    for (int kk = 0; kk < 16; kk++) {
      float4 av = *reinterpret_cast<const float4*>(&As[kk][ty << 2]);
      float4 bv = *reinterpret_cast<const float4*>(&Bs[kk][tx << 2]);
      acc[0][0] += av.x * bv.x; acc[0][1] += av.x * bv.y; acc[0][2] += av.x * bv.z; acc[0][3] += av.x * bv.w;
      acc[1][0] += av.y * bv.x; acc[1][1] += av.y * bv.y; acc[1][2] += av.y * bv.z; acc[1][3] += av.y * bv.w;
      acc[2][0] += av.z * bv.x; acc[2][1] += av.z * bv.y; acc[2][2] += av.z * bv.z; acc[2][3] += av.z * bv.w;
      acc[3][0] += av.w * bv.x; acc[3][1] += av.w * bv.y; acc[3][2] += av.w * bv.z; acc[3][3] += av.w * bv.w;
    }
    __syncthreads();
  }

  int gn0 = n0 + (tx << 2);
#pragma unroll
  for (int i = 0; i < 4; i++) {
    int gm = m0 + (ty << 2) + i;
    if (gm >= M) break;
    float4 v = make_float4(acc[i][0], acc[i][1], acc[i][2], acc[i][3]);
    if constexpr (EPI == 1) {
      float4 bb = *(const float4*)(bias + gn0);
      float4 rr = *(const float4*)(resid + (size_t)gm * N + gn0);
      v.x += bb.x + rr.x; v.y += bb.y + rr.y; v.z += bb.z + rr.z; v.w += bb.w + rr.w;
      *(float4*)(outF + (size_t)gm * N + gn0) = v;
    } else {
      *(float4*)(outF + (size_t)gm * N + gn0) = v;
    }
  }
}

// ---------- pooled-token index decode ----------
__device__ __forceinline__ void decode_l(int l, int& gi, int& ph, int& pw,
                                         int& oh, int& ow, int& base) {
  if (l < 64)       { gi = 0; base = 0;   oh = 8; ow = 8; }
  else if (l < 100) { gi = 1; base = 64;  oh = 6; ow = 6; }
  else if (l < 125) { gi = 2; base = 100; oh = 5; ow = 5; }
  else              { gi = 3; base = 125; oh = 4; ow = 4; }
  int loc = l - base;
  ph = loc / ow; pw = loc % ow;
}

// ---------- pooling stage A: per bin-row-chunk partial sums ----------
__global__ __launch_bounds__(256) void pool_partial(const unsigned short* __restrict__ xn,
                                                    float* __restrict__ partial) {
  const int gid = blockIdx.x;
  const int b = gid / NUNIT, u = gid % NUNIT;
  int ow_, cr, ubase;
  if (u < 256)      { ubase = 0;   ow_ = 8; cr = 3; }
  else if (u < 400) { ubase = 256; ow_ = 6; cr = 4; }
  else if (u < 500) { ubase = 400; ow_ = 5; cr = 5; }
  else              { ubase = 500; ow_ = 4; cr = 6; }
  const int v = u - ubase;
  const int bin = v >> 2, chunk = v & 3;
  const int ph = bin / ow_, pw = bin % ow_;
  const int sh = (ph * HH) / ow_;
  const int sw = (pw * WW) / ow_, ew = ((pw + 1) * WW + ow_ - 1) / ow_;
  const int y0 = sh + chunk * cr, y1 = y0 + cr;

  const int tid = threadIdx.x;
  const int cg = tid & 63, pl = tid >> 6;
  const unsigned short* xb = xn + (size_t)b * NN * CC + (cg << 3);

  float acc[8] = {0.f, 0.f, 0.f, 0.f, 0.f, 0.f, 0.f, 0.f};
  for (int y = y0; y < y1; y++) {
    const unsigned short* xr = xb + (size_t)(y * WW) * CC;
    for (int xx = sw + pl; xx < ew; xx += 4) {
      int4 vv = *(const int4*)(xr + (size_t)xx * CC);
      unsigned ua = (unsigned)vv.x, ub = (unsigned)vv.y,
               uc = (unsigned)vv.z, ud = (unsigned)vv.w;
      acc[0] += bflo(ua); acc[1] += bfhi(ua);
      acc[2] += bflo(ub); acc[3] += bfhi(ub);
      acc[4] += bflo(uc); acc[5] += bfhi(uc);
      acc[6] += bflo(ud); acc[7] += bfhi(ud);
    }
  }
  __shared__ float red[4][64][8];
#pragma unroll
  for (int j = 0; j < 8; j++) red[pl][cg][j] = acc[j];
  __syncthreads();
  if (tid < 64) {
    float s[8];
#pragma unroll
    for (int j = 0; j < 8; j++)
      s[j] = red[0][tid][j] + red[1][tid][j] + red[2][tid][j] + red[3][tid][j];
    float* dst = partial + (size_t)gid * CC + (tid << 3);
    *(float4*)dst = make_float4(s[0], s[1], s[2], s[3]);
    *(float4*)(dst + 4) = make_float4(s[4], s[5], s[6], s[7]);
  }
}

// ---------- pooling stage B: sum 4 chunk-partials, apply 1/area ----------
__global__ __launch_bounds__(256) void pool_reduce(const float* __restrict__ partial,
                                                   float* __restrict__ pr) {
  const int bl = blockIdx.x;
  const int b = bl / LL, l = bl % LL;
  int gi, ph, pw, oh, ow, base; decode_l(l, gi, ph, pw, oh, ow, base);
  const int sh = (ph * HH) / oh, eh = ((ph + 1) * HH + oh - 1) / oh;
  const int sw = (pw * WW) / ow, ew = ((pw + 1) * WW + ow - 1) / ow;
  const float inv_area = 1.f / (float)((eh - sh) * (ew - sw));
  int u0;
  if (l < 64)       u0 = l * 4;
  else if (l < 100) u0 = 256 + (l - 64) * 4;
  else if (l < 125) u0 = 400 + (l - 100) * 4;
  else              u0 = 500 + (l - 125) * 4;
  const float* p0 = partial + ((size_t)(b * NUNIT + u0)) * CC;
  const int c = threadIdx.x << 1;
  float2 a0 = *(const float2*)(p0 + c);
  float2 a1 = *(const float2*)(p0 + CC + c);
  float2 a2 = *(const float2*)(p0 + 2 * CC + c);
  float2 a3 = *(const float2*)(p0 + 3 * CC + c);
  float2 r;
  r.x = (a0.x + a1.x + a2.x + a3.x) * inv_area;
  r.y = (a0.y + a1.y + a2.y + a3.y) * inv_area;
  *(float2*)(pr + ((size_t)(b * LL + l)) * CC + c) = r;
}

// ---------- pool += dwconv3x3(pool) + bias ----------
__global__ __launch_bounds__(256) void pool_dwconv(const float* __restrict__ pin,
                                                   const float* __restrict__ dw,
                                                   const float* __restrict__ db,
                                                   float* __restrict__ pout) {
  int bl = blockIdx.x;
  int b = bl / LL, l = bl % LL;
  int gi, ph, pw, oh, ow, base; decode_l(l, gi, ph, pw, oh, ow, base);
  for (int c = threadIdx.x; c < CC; c += 256) {
    float acc = db[gi * CC + c];
#pragma unroll
    for (int dy = -1; dy <= 1; dy++) {
      int y = ph + dy; if ((unsigned)y >= (unsigned)oh) continue;
#pragma unroll
      for (int dx = -1; dx <= 1; dx++) {
        int x = pw + dx; if ((unsigned)x >= (unsigned)ow) continue;
        acc += dw[((size_t)(gi * CC + c)) * 9 + (dy + 1) * 3 + (dx + 1)] *
               pin[((size_t)(b * LL) + base + y * ow + x) * CC + c];
      }
    }
    pout[((size_t)(b * LL + l)) * CC + c] =
        pin[((size_t)(b * LL + l)) * CC + c] + acc;
  }
}

// ---------- kv prep: f32 kv -> pre-swizzled bf16 K and V^T per (b,h) ----------
__global__ __launch_bounds__(256) void kvprep(const float* __restrict__ kvb,
                                              unsigned short* __restrict__ kpack,
                                              unsigned short* __restrict__ vtpack) {
  const int bh = blockIdx.x;
  const int b = bh >> 3, h = bh & 7;
  unsigned short* kd = kpack + (size_t)bh * 10240;
  unsigned short* vd = vtpack + (size_t)bh * 12288;
  for (int idx = threadIdx.x; idx < 1280; idx += 256) {
    const int row = idx >> 3, blk = idx & 7;
    int4 pk = make_int4(0, 0, 0, 0);
    if (row < LL) {
      const float* kp = kvb + ((size_t)(b * LL + row) << 10) + (h << 6) + (blk << 3);
      float4 v0 = *(const float4*)kp;
      float4 v1 = *(const float4*)(kp + 4);
      pk.x = (int)packbf(v0.x, v0.y); pk.y = (int)packbf(v0.z, v0.w);
      pk.z = (int)packbf(v1.x, v1.y); pk.w = (int)packbf(v1.z, v1.w);
    }
    *(int4*)(kd + row * 64 + ((blk ^ (row & 7)) << 3)) = pk;
    const int l = row, d0 = blk << 3, lb = l >> 3;
    unsigned short vv[8] = {0, 0, 0, 0, 0, 0, 0, 0};
    if (l < LL) {
      const float* vp = kvb + ((size_t)(b * LL + l) << 10) + 512 + (h << 6) + d0;
      float4 v0 = *(const float4*)vp;
      float4 v1 = *(const float4*)(vp + 4);
      vv[0] = f2bf(v0.x); vv[1] = f2bf(v0.y); vv[2] = f2bf(v0.z); vv[3] = f2bf(v0.w);
      vv[4] = f2bf(v1.x); vv[5] = f2bf(v1.y); vv[6] = f2bf(v1.z); vv[7] = f2bf(v1.w);
    }
#pragma unroll
    for (int j = 0; j < 8; j++) {
      const int d = d0 + j;
      vd[d * 192 + ((lb ^ (d & 7)) << 3) + (l & 7)] = vv[j];
    }
  }
}

// ---------- MFMA fused attention (pure gld_lds staging from pre-swizzled kv) ----------
__global__ __launch_bounds__(256) void attn_mfma(const unsigned short* __restrict__ q,
                                                 const unsigned short* __restrict__ kpack,
                                                 const unsigned short* __restrict__ vtpack,
                                                 unsigned short* __restrict__ out) {
  __shared__ __align__(16) unsigned short Ks[160 * 64];
  __shared__ __align__(16) unsigned short Vt[64 * 192];
  __shared__ __align__(16) unsigned short Pl[4 * 16 * 192];
  const int bh = blockIdx.x;
  const int b = bh >> 3;
  const int tid = threadIdx.x;
  const int w = tid >> 6, lane = tid & 63;

  const unsigned short* kg = kpack + (size_t)bh * 10240;
  const unsigned short* vg = vtpack + (size_t)bh * 12288;
#pragma unroll
  for (int p = 0; p < 5; p++)
    gld_lds16(kg + (p << 11) + (tid << 3), Ks + (p << 11) + (w << 9));
#pragma unroll
  for (int p = 0; p < 6; p++)
    gld_lds16(vg + (p << 11) + (tid << 3), Vt + (p << 11) + (w << 9));

  const int qrow = blockIdx.y * 64 + w * 16 + (lane & 15);
  const unsigned short* qp = q + ((size_t)(b * NN + qrow) << 9) + ((bh & 7) << 6) + ((lane >> 4) << 3);
  bf16x8 qf0 = *(const bf16x8*)qp;
  bf16x8 qf1 = *(const bf16x8*)(qp + 32);

  __syncthreads();

  f32x4 s[9];
  const int kb = lane >> 4;
  const int mycol = lane & 15;
#pragma unroll
  for (int lt = 0; lt < 9; lt++) {
    int lcol = lt * 16 + mycol;
    const unsigned short* kr = Ks + lcol * 64;
    bf16x8 k0 = *(const bf16x8*)(kr + ((kb ^ (lcol & 7)) << 3));
    bf16x8 k1 = *(const bf16x8*)(kr + (((kb + 4) ^ (lcol & 7)) << 3));
    f32x4 a = (f32x4){0.f, 0.f, 0.f, 0.f};
    a = __builtin_amdgcn_mfma_f32_16x16x32_bf16(qf0, k0, a, 0, 0, 0);
    a = __builtin_amdgcn_mfma_f32_16x16x32_bf16(qf1, k1, a, 0, 0, 0);
    s[lt] = a;
  }
#pragma unroll
  for (int lt = 0; lt < 9; lt++) {
#pragma unroll
    for (int j = 0; j < 4; j++) {
      float v = s[lt][j] * 0.125f;
      if (lt == 8 && mycol >= 13) v = -1e30f;
      s[lt][j] = v;
    }
  }
  float sm[4];
#pragma unroll
  for (int j = 0; j < 4; j++) {
    float m = s[0][j];
#pragma unroll
    for (int lt = 1; lt < 9; lt++) m = fmaxf(m, s[lt][j]);
#pragma unroll
    for (int off = 1; off < 16; off <<= 1) m = fmaxf(m, __shfl_xor(m, off, 64));
    float su = 0.f;
#pragma unroll
    for (int lt = 0; lt < 9; lt++) {
      float p = __expf(s[lt][j] - m);
      s[lt][j] = p;
      su += p;
    }
#pragma unroll
    for (int off = 1; off < 16; off <<= 1) su += __shfl_xor(su, off, 64);
    sm[j] = su;
  }

  unsigned short* Pw = Pl + w * (16 * 192);
#pragma unroll
  for (int lt = 0; lt < 9; lt++) {
#pragma unroll
    for (int j = 0; j < 4; j++) {
      int qr_ = (lane >> 4) * 4 + j;
      int lcol = lt * 16 + mycol;
      Pw[qr_ * 192 + (((lcol >> 3) ^ (qr_ & 7)) << 3) + (lcol & 7)] = f2bf(s[lt][j]);
    }
  }
#pragma unroll
  for (int j = 0; j < 4; j++) {
    int qr_ = mycol;
    int lcol = 144 + (lane >> 4) * 4 + j;
    Pw[qr_ * 192 + (((lcol >> 3) ^ (qr_ & 7)) << 3) + (lcol & 7)] = 0;
  }
  __syncthreads();

  f32x4 o[4];
#pragma unroll
  for (int dt = 0; dt < 4; dt++) o[dt] = (f32x4){0.f, 0.f, 0.f, 0.f};
#pragma unroll
  for (int lc = 0; lc < 5; lc++) {
    int lb = lc * 4 + (lane >> 4);
    bf16x8 pa = *(const bf16x8*)(Pw + mycol * 192 + ((lb ^ (mycol & 7)) << 3));
#pragma unroll
    for (int dt = 0; dt < 4; dt++) {
      int d = dt * 16 + mycol;
      bf16x8 vb = *(const bf16x8*)(Vt + d * 192 + ((lb ^ (d & 7)) << 3));
      o[dt] = __builtin_amdgcn_mfma_f32_16x16x32_bf16(pa, vb, o[dt], 0, 0, 0);
    }
  }

  float inv[4];
#pragma unroll
  for (int j = 0; j < 4; j++) inv[j] = 1.f / sm[j];
#pragma unroll
  for (int dt = 0; dt < 4; dt++) {
#pragma unroll
    for (int j = 0; j < 4; j++) {
      int qg = blockIdx.y * 64 + w * 16 + (lane >> 4) * 4 + j;
      out[((size_t)(b * NN + qg) << 9) + ((bh & 7) << 6) + dt * 16 + mycol] =
          f2bf(o[dt][j] * inv[j]);
    }
  }
}

// ---------- depthwise 3x3 sliding-window; grid (384, n_images) ----------
__device__ __forceinline__ void dw_ldcol(const unsigned short* __restrict__ img,
                                         int hh, int xx, int o0, float* __restrict__ f) {
  const bool xok = (unsigned)xx < (unsigned)WW;
#pragma unroll
  for (int r = 0; r < 3; r++) {
    const int y = hh - 1 + r;
    int4 v = make_int4(0, 0, 0, 0);
    if (xok && (unsigned)y < (unsigned)HH)
      v = *(const int4*)(img + ((size_t)(y * WW + xx) * HID) + o0);
    unsigned ua = (unsigned)v.x, ub = (unsigned)v.y,
             uc = (unsigned)v.z, ud = (unsigned)v.w;
    f[r * 8 + 0] = bflo(ua); f[r * 8 + 1] = bfhi(ua);
    f[r * 8 + 2] = bflo(ub); f[r * 8 + 3] = bfhi(ub);
    f[r * 8 + 4] = bflo(uc); f[r * 8 + 5] = bfhi(uc);
    f[r * 8 + 6] = bflo(ud); f[r * 8 + 7] = bfhi(ud);
  }
}

__device__ __forceinline__ void dw_emit(const float wr[9][8], const float bs[8],
                                        const float* __restrict__ A,
                                        const float* __restrict__ B,
                                        const float* __restrict__ C,
                                        unsigned short* __restrict__ t2,
                                        int hh, int xx, int o0) {
  float acc[8];
#pragma unroll
  for (int j = 0; j < 8; j++) acc[j] = bs[j];
#pragma unroll
  for (int r = 0; r < 3; r++) {
#pragma unroll
    for (int j = 0; j < 8; j++) {
      acc[j] += wr[r * 3 + 0][j] * A[r * 8 + j];
      acc[j] += wr[r * 3 + 1][j] * B[r * 8 + j];
      acc[j] += wr[r * 3 + 2][j] * C[r * 8 + j];
    }
  }
  int4 o;
  o.x = (int)packbf(hswish(acc[0]), hswish(acc[1]));
  o.y = (int)packbf(hswish(acc[2]), hswish(acc[3]));
  o.z = (int)packbf(hswish(acc[4]), hswish(acc[5]));
  o.w = (int)packbf(hswish(acc[6]), hswish(acc[7]));
  *(int4*)(t2 + ((size_t)(hh * WW + xx) * HID) + o0) = o;
}

__global__ __launch_bounds__(256) void dwconv_hid(const unsigned short* __restrict__ t1,
                                                  const float* __restrict__ wt,
                                                  const float* __restrict__ bias,
                                                  unsigned short* __restrict__ t2) {
  const int bx = blockIdx.x;            // 0..383
  const size_t ioff = (size_t)blockIdx.y * NN * HID;
  const unsigned short* t1i = t1 + ioff;
  unsigned short* t2i = t2 + ioff;
  const int hh = bx >> 2, quarter = bx & 3;
  const int x0 = quarter * 24;
  const int o0 = threadIdx.x << 3;

  float wr[9][8];
#pragma unroll
  for (int k = 0; k < 9; k++) {
    float4 w0 = *(const float4*)(wt + k * HID + o0);
    float4 w1 = *(const float4*)(wt + k * HID + o0 + 4);
    wr[k][0] = w0.x; wr[k][1] = w0.y; wr[k][2] = w0.z; wr[k][3] = w0.w;
    wr[k][4] = w1.x; wr[k][5] = w1.y; wr[k][6] = w1.z; wr[k][7] = w1.w;
  }
  float bs[8];
  {
    float4 b0 = *(const float4*)(bias + o0);
    float4 b1 = *(const float4*)(bias + o0 + 4);
    bs[0] = b0.x; bs[1] = b0.y; bs[2] = b0.z; bs[3] = b0.w;
    bs[4] = b1.x; bs[5] = b1.y; bs[6] = b1.z; bs[7] = b1.w;
  }

  float cm[24], cc[24], cn[24];
  dw_ldcol(t1i, hh, x0 - 1, o0, cm);
  dw_ldcol(t1i, hh, x0, o0, cc);
  for (int xx = x0; xx < x0 + 24; xx += 3) {
    dw_ldcol(t1i, hh, xx + 1, o0, cn);
    dw_emit(wr, bs, cm, cc, cn, t2i, hh, xx, o0);
    dw_ldcol(t1i, hh, xx + 2, o0, cm);
    dw_emit(wr, bs, cc, cn, cm, t2i, hh, xx + 1, o0);
    dw_ldcol(t1i, hh, xx + 3, o0, cc);
    dw_emit(wr, bs, cn, cm, cc, t2i, hh, xx + 2, o0);
  }
}

// ---------- launch ----------
extern "C" void kernel_launch(void* const* d_in, const int* in_sizes, int n_in,
                              void* d_out, int out_size, void* d_ws, size_t ws_size,
                              hipStream_t stream) {
  const float* x        = (const float*)d_in[0];
  const float* norm1_g  = (const float*)d_in[1];
  const float* norm1_b  = (const float*)d_in[2];
  const float* q_w      = (const float*)d_in[3];
  const float* kv_w     = (const float*)d_in[4];
  const float* anorm_g  = (const float*)d_in[5];
  const float* anorm_b  = (const float*)d_in[6];
  const float* proj_w   = (const float*)d_in[7];
  const float* proj_b   = (const float*)d_in[8];
  const float* dconv_w  = (const float*)d_in[9];
  const float* dconv_b  = (const float*)d_in[10];
  const float* norm2_g  = (const float*)d_in[11];
  const float* norm2_b  = (const float*)d_in[12];
  const float* fc1_w    = (const float*)d_in[13];
  const float* fc1_b    = (const float*)d_in[14];
  const float* conv_w   = (const float*)d_in[15];
  const float* conv_b   = (const float*)d_in[16];
  const float* fc2_w    = (const float*)d_in[17];
  const float* fc2_b    = (const float*)d_in[18];
  float* out = (float*)d_out;

  char* ws = (char*)d_ws;
  const size_t SZ_BIG = (size_t)BB * NN * CC * 2;          // 37,748,736
  unsigned short* bufA = (unsigned short*)(ws);
  unsigned short* bufB = (unsigned short*)(ws + SZ_BIG);
  unsigned short* bufC = (unsigned short*)(ws + 2 * SZ_BIG);
  // weights (persistent through launch)
  char* wbase = ws + 3 * SZ_BIG;
  unsigned short* qw16   = (unsigned short*)(wbase);                  // 524288 B
  unsigned short* pw16   = (unsigned short*)(wbase + 524288);         // 524288 B
  unsigned short* fc1w16 = (unsigned short*)(wbase + 1048576);        // 2097152 B
  unsigned short* fc2w16 = (unsigned short*)(wbase + 3145728);        // 2097152 B
  float* wt              = (float*)(wbase + 5242880);                 // 73728 B
  // kvb (dead after kvprep)
  float* kvb = (float*)(wbase + 5316608);                             // 2310144 B
  // scratch (phase-overlapped)
  char* sb = wbase + 7626752;
  float* pools_raw = (float*)(sb);                                    // 1155072 B
  float* pools_c   = (float*)(sb + 1155072);
  float* pools_n   = (float*)(sb + 2 * 1155072);
  float* pool_part = (float*)(sb + 3 * 1155072);                      // 4620288 B
  // kpack/vtpack written after pools are dead
  unsigned short* kpack  = (unsigned short*)(sb);                     // 655360 B
  unsigned short* vtpack = (unsigned short*)(sb + 655360);            // 786432 B
  // batched-IRB t2 (written after kvb/pools/kpack all dead)
  unsigned short* t2b = (unsigned short*)(wbase + 5316608);           // 75497472 B
  const size_t need_batched =
      3 * SZ_BIG + 5316608ull + (size_t)2 * NN * HID * 2;             // 194,060,288
  const bool batched = ws_size >= need_batched;

  const int ROWS = BB * NN;   // 36864

  w2bf<<<(262144 / 4 + 255) / 256, 256, 0, stream>>>(q_w, qw16, 262144 / 4);
  w2bf<<<(262144 / 4 + 255) / 256, 256, 0, stream>>>(proj_w, pw16, 262144 / 4);
  w2bf<<<(1048576 / 4 + 255) / 256, 256, 0, stream>>>(fc1_w, fc1w16, 1048576 / 4);
  w2bf<<<(1048576 / 4 + 255) / 256, 256, 0, stream>>>(fc2_w, fc2w16, 1048576 / 4);
  wtrans<<<(9 * HID + 255) / 256, 256, 0, stream>>>(conv_w, wt);

  ln_kernel<1><<<ROWS, 256, 0, stream>>>(x, norm1_g, norm1_b, bufA);
  gemm_mfma<3><<<dim3(ROWS / 128, CC / 128), 256, 0, stream>>>(
      bufA, qw16, nullptr, nullptr, nullptr, bufB, ROWS, CC, CC);
  pool_partial<<<BB * NUNIT, 256, 0, stream>>>(bufA, pool_part);
  pool_reduce<<<BB * LL, 256, 0, stream>>>(pool_part, pools_raw);
  pool_dwconv<<<BB * LL, 256, 0, stream>>>(pools_raw, dconv_w, dconv_b, pools_c);
  ln_kernel<0><<<BB * LL, 256, 0, stream>>>(pools_c, anorm_g, anorm_b, pools_n);
  gemm_xwt<float, 0><<<dim3((BB * LL + 63) / 64, (2 * CC) / 64), 256, 0, stream>>>(
      pools_n, kv_w, nullptr, nullptr, kvb, nullptr, BB * LL, 2 * CC, CC);
  kvprep<<<BB * NHEAD, 256, 0, stream>>>(kvb, kpack, vtpack);
  attn_mfma<<<dim3(BB * NHEAD, NN / 64), 256, 0, stream>>>(bufB, kpack, vtpack, bufC);
  gemm_mfma<1><<<dim3(ROWS / 128, CC / 128), 256, 0, stream>>>(
      bufC, pw16, proj_b, x, out, nullptr, ROWS, CC, CC);
  ln_kernel<1><<<ROWS, 256, 0, stream>>>(out, norm2_g, norm2_b, bufC);

  if (batched) {
    for (int g = 0; g < 2; g++) {
      const unsigned short* xn2g = bufC + (size_t)g * 2 * NN * CC;
      float* outg = out + (size_t)g * 2 * NN * CC;
      gemm_mfma<2><<<dim3(2 * NN / 128, HID / 128), 256, 0, stream>>>(
          xn2g, fc1w16, fc1_b, nullptr, nullptr, bufA, 2 * NN, HID, CC);
      dwconv_hid<<<dim3(384, 2), 256, 0, stream>>>(bufA, wt, conv_b, t2b);
      gemm_mfma<1><<<dim3(2 * NN / 128, CC / 128), 256, 0, stream>>>(
          t2b, fc2w16, fc2_b, outg, outg, nullptr, 2 * NN, CC, HID);
    }
  } else {
    for (int b = 0; b < BB; b++) {
      const unsigned short* xn2b = bufC + (size_t)b * NN * CC;
      gemm_mfma<2><<<dim3(NN / 128, HID / 128), 256, 0, stream>>>(
          xn2b, fc1w16, fc1_b, nullptr, nullptr, bufA, NN, HID, CC);
      dwconv_hid<<<dim3(384, 1), 256, 0, stream>>>(bufA, wt, conv_b, bufB);
      gemm_mfma<1><<<dim3(NN / 128, CC / 128), 256, 0, stream>>>(
          bufB, fc2w16, fc2_b, out + (size_t)b * NN * CC, out + (size_t)b * NN * CC,
          nullptr, NN, CC, HID);
    }
  }
}

// Round 19
// 619.445 us; speedup vs baseline: 1.0223x; 1.0110x over previous
//
#include <hip/hip_runtime.h>
#include <hip/hip_bf16.h>

// Problem constants (fixed by setup_inputs).
#define BB 4
#define HH 96
#define WW 96
#define CC 512
#define NN 9216           // H*W
#define LL 141            // 64+36+25+16 pooled tokens
#define HID 2048
#define NHEAD 8
#define HD 64
#define NUNIT 564         // pool bin-chunks per image: 64*4+36*4+25*4+16*4

typedef __attribute__((ext_vector_type(8))) short bf16x8;
typedef __attribute__((ext_vector_type(4))) float f32x4;

// ---------- helpers ----------
__device__ __forceinline__ unsigned short f2bf(float f) {
  unsigned u = __float_as_uint(f);
  u = (u + 0x7fffu + ((u >> 16) & 1u)) >> 16;   // RNE
  return (unsigned short)u;
}
__device__ __forceinline__ float bf2f(unsigned short s) {
  return __uint_as_float((unsigned)s << 16);
}
__device__ __forceinline__ float bflo(unsigned u) { return __uint_as_float(u << 16); }
__device__ __forceinline__ float bfhi(unsigned u) { return __uint_as_float(u & 0xffff0000u); }
__device__ __forceinline__ unsigned packbf(float a, float b) {
  return (unsigned)f2bf(a) | ((unsigned)f2bf(b) << 16);
}
__device__ __forceinline__ float hswish(float x) {
  return x * fminf(fmaxf(x + 3.f, 0.f), 6.f) * (1.f / 6.f);
}
__device__ __forceinline__ void gld_lds16(const void* g, void* l) {
  __builtin_amdgcn_global_load_lds(
      (const __attribute__((address_space(1))) void*)g,
      (__attribute__((address_space(3))) void*)l, 16, 0, 0);
}

// ---------- f32 -> bf16 weight conversion ----------
__global__ __launch_bounds__(256) void w2bf(const float* __restrict__ in,
                                            unsigned short* __restrict__ out, int n4) {
  int i = blockIdx.x * 256 + threadIdx.x;
  if (i >= n4) return;
  float4 v = ((const float4*)in)[i];
  ushort4 o;
  o.x = f2bf(v.x); o.y = f2bf(v.y); o.z = f2bf(v.z); o.w = f2bf(v.w);
  ((ushort4*)out)[i] = o;
}

// ---------- conv_w [HID][9] -> wt [9][HID] ----------
__global__ __launch_bounds__(256) void wtrans(const float* __restrict__ w,
                                              float* __restrict__ wt) {
  int i = blockIdx.x * 256 + threadIdx.x;
  if (i >= 9 * HID) return;
  int k = i / HID, c = i - k * HID;
  wt[i] = w[c * 9 + k];
}

// ---------- LayerNorm over C=512, one block per row ----------
template <int OUTBF>
__global__ __launch_bounds__(256) void ln_kernel(const float* __restrict__ in,
                                                 const float* __restrict__ g,
                                                 const float* __restrict__ be,
                                                 void* __restrict__ outp) {
  int r = blockIdx.x;
  int t = threadIdx.x;
  const float* p = in + ((size_t)r << 9);
  float2 v = *(const float2*)(p + (t << 1));
  float s = v.x + v.y;
  float sq = v.x * v.x + v.y * v.y;
#pragma unroll
  for (int off = 32; off > 0; off >>= 1) {
    s += __shfl_down(s, off, 64);
    sq += __shfl_down(sq, off, 64);
  }
  __shared__ float red[8];
  int wid = t >> 6;
  if ((t & 63) == 0) { red[wid] = s; red[4 + wid] = sq; }
  __syncthreads();
  float ts = red[0] + red[1] + red[2] + red[3];
  float tq = red[4] + red[5] + red[6] + red[7];
  float mu = ts * (1.f / 512.f);
  float var = tq * (1.f / 512.f) - mu * mu;
  float inv = rsqrtf(var + 1e-5f);
  float2 gg = *(const float2*)(g + (t << 1));
  float2 bb = *(const float2*)(be + (t << 1));
  float ox = (v.x - mu) * inv * gg.x + bb.x;
  float oy = (v.y - mu) * inv * gg.y + bb.y;
  if constexpr (OUTBF) {
    ((unsigned*)outp)[((size_t)r << 8) + t] = packbf(ox, oy);
  } else {
    *(float2*)((float*)outp + ((size_t)r << 9) + (t << 1)) = make_float2(ox, oy);
  }
}

// ---------- MFMA GEMM: C = A[M,K](bf16) @ W[N,K](bf16)^T ----------
// BEST MEASURED CONFIG (round 10/16): BK=64, double-buffered LDS (64 KB),
// 2-deep counted-vmcnt pipeline: prologue stages tiles 0,1; iter t waits
// vmcnt(8) (tile t+1 stays in flight across the barrier), ds_reads frags,
// lgkmcnt(0)+barrier, STAGE(t+2) into the just-read buffer, 32 MFMA.
// vmcnt(0) only on final iter. Bank-conflict-free via source-side XOR
// swizzle (LDS k-block b of row r holds global k-block b ^ (r&7)).
template <int EPI>
__global__ __launch_bounds__(256) void gemm_mfma(const unsigned short* __restrict__ A,
                                                 const unsigned short* __restrict__ W,
                                                 const float* __restrict__ bias,
                                                 const float* __restrict__ resid,
                                                 float* __restrict__ outF,
                                                 unsigned short* __restrict__ outB,
                                                 int M, int N, int K) {
  __shared__ __align__(16) unsigned short As[2][128 * 64];   // 2 x 16 KB
  __shared__ __align__(16) unsigned short Bs[2][128 * 64];   // 2 x 16 KB
  const int tid = threadIdx.x;
  const int w = tid >> 6;
  const int l = tid & 63;
  const int m0 = blockIdx.x * 128;
  const int n0 = blockIdx.y * 128;
  const int wr = (w >> 1) << 6;
  const int wc = (w & 1) << 6;

  const int srow = tid >> 3;                         // 0..31
  const int skk = ((tid & 7) ^ (srow & 7)) << 3;     // pre-swizzled k elem offset
  const size_t a_row = (size_t)(m0 + srow) * K + skk;
  const size_t b_row = (size_t)(n0 + srow) * K + skk;
  const size_t rs = (size_t)32 * K;
  const int ld0 = w << 9;                            // wave slot (512 ushorts)

#define STAGE_G(d, k0)                                                      \
  {                                                                         \
    gld_lds16(A + a_row + (k0),          &As[d][ld0]);                      \
    gld_lds16(A + a_row + rs + (k0),     &As[d][2048 + ld0]);               \
    gld_lds16(A + a_row + 2 * rs + (k0), &As[d][4096 + ld0]);               \
    gld_lds16(A + a_row + 3 * rs + (k0), &As[d][6144 + ld0]);               \
    gld_lds16(W + b_row + (k0),          &Bs[d][ld0]);                      \
    gld_lds16(W + b_row + rs + (k0),     &Bs[d][2048 + ld0]);               \
    gld_lds16(W + b_row + 2 * rs + (k0), &Bs[d][4096 + ld0]);               \
    gld_lds16(W + b_row + 3 * rs + (k0), &Bs[d][6144 + ld0]);               \
  }

  f32x4 acc[4][4];
#pragma unroll
  for (int i = 0; i < 4; i++)
#pragma unroll
    for (int j = 0; j < 4; j++) acc[i][j] = (f32x4){0.f, 0.f, 0.f, 0.f};

  const int fr = l & 15;
  const int kb = l >> 4;                              // 0..3
  const int x0 = ((kb ^ (fr & 7)) << 3);              // swizzled read offsets
  const int x1 = (((kb + 4) ^ (fr & 7)) << 3);
  const int ar0 = (wr + fr) * 64;
  const int br0 = (wc + fr) * 64;

  const int nt = K >> 6;                              // >= 2 for all our shapes
  STAGE_G(0, 0);
  STAGE_G(1, 64);

  int cur = 0;
  for (int t = 0; t < nt; ++t) {
    if (t + 1 < nt)
      asm volatile("s_waitcnt vmcnt(8)" ::: "memory");
    else
      asm volatile("s_waitcnt vmcnt(0)" ::: "memory");
    __builtin_amdgcn_s_barrier();

    bf16x8 a0[4], a1[4], b0[4], b1[4];
#pragma unroll
    for (int i = 0; i < 4; i++) {
      a0[i] = *(const bf16x8*)(&As[cur][ar0 + i * 1024 + x0]);
      a1[i] = *(const bf16x8*)(&As[cur][ar0 + i * 1024 + x1]);
      b0[i] = *(const bf16x8*)(&Bs[cur][br0 + i * 1024 + x0]);
      b1[i] = *(const bf16x8*)(&Bs[cur][br0 + i * 1024 + x1]);
    }
    asm volatile("s_waitcnt lgkmcnt(0)" ::: "memory");
    __builtin_amdgcn_s_barrier();          // all waves done reading buf[cur]
    if (t + 2 < nt) STAGE_G(cur, (size_t)(t + 2) << 6);

#pragma unroll
    for (int mi = 0; mi < 4; mi++)
#pragma unroll
      for (int ni = 0; ni < 4; ni++) {
        acc[mi][ni] = __builtin_amdgcn_mfma_f32_16x16x32_bf16(a0[mi], b0[ni],
                                                              acc[mi][ni], 0, 0, 0);
        acc[mi][ni] = __builtin_amdgcn_mfma_f32_16x16x32_bf16(a1[mi], b1[ni],
                                                              acc[mi][ni], 0, 0, 0);
      }
    cur ^= 1;
  }
#undef STAGE_G

  const int r4 = (l >> 4) << 2;
  float bval[4];
  if constexpr (EPI == 1 || EPI == 2) {
#pragma unroll
    for (int ni = 0; ni < 4; ni++) bval[ni] = bias[n0 + wc + ni * 16 + fr];
  }
#pragma unroll
  for (int mi = 0; mi < 4; mi++) {
#pragma unroll
    for (int j = 0; j < 4; j++) {
      const int gm = m0 + wr + mi * 16 + r4 + j;
#pragma unroll
      for (int ni = 0; ni < 4; ni++) {
        const int gn = n0 + wc + ni * 16 + fr;
        float v = acc[mi][ni][j];
        if constexpr (EPI == 1) {
          v += bval[ni] + resid[(size_t)gm * N + gn];
          outF[(size_t)gm * N + gn] = v;
        } else if constexpr (EPI == 2) {
          outB[(size_t)gm * N + gn] = f2bf(hswish(v + bval[ni]));
        } else if constexpr (EPI == 3) {
          outB[(size_t)gm * N + gn] = f2bf(v);
        } else {
          outF[(size_t)gm * N + gn] = v;
        }
      }
    }
  }
}

// ---------- small vector GEMM (kv only) ----------
template <typename AT, int EPI>
__global__ __launch_bounds__(256) void gemm_xwt(const AT* __restrict__ A,
                                                const float* __restrict__ Wt,
                                                const float* __restrict__ bias,
                                                const float* __restrict__ resid,
                                                float* __restrict__ outF,
                                                unsigned short* __restrict__ outB,
                                                int M, int N, int K) {
  __shared__ __align__(16) float As[16][68];
  __shared__ __align__(16) float Bs[16][68];
  int tid = threadIdx.x;
  int m0 = blockIdx.x * 64;
  int n0 = blockIdx.y * 64;
  int lr = tid >> 2;
  int lc = (tid & 3) << 2;
  int ty = tid >> 4, tx = tid & 15;
  float acc[4][4] = {};
  int grA = m0 + lr; if (grA > M - 1) grA = M - 1;
  const size_t arow = (size_t)grA * K + lc;
  const size_t brow = (size_t)(n0 + lr) * K + lc;

  for (int k0 = 0; k0 < K; k0 += 16) {
    float a0, a1, a2, a3;
    if constexpr (sizeof(AT) == 4) {
      float4 v = *reinterpret_cast<const float4*>(A + arow + k0);
      a0 = v.x; a1 = v.y; a2 = v.z; a3 = v.w;
    } else {
      ushort4 v = *reinterpret_cast<const ushort4*>(A + arow + k0);
      a0 = bf2f(v.x); a1 = bf2f(v.y); a2 = bf2f(v.z); a3 = bf2f(v.w);
    }
    float4 wv = *reinterpret_cast<const float4*>(Wt + brow + k0);
    As[lc + 0][lr] = a0; As[lc + 1][lr] = a1; As[lc + 2][lr] = a2; As[lc + 3][lr] = a3;
    Bs[lc + 0][lr] = wv.x; Bs[lc + 1][lr] = wv.y; Bs[lc + 2][lr] = wv.z; Bs[lc + 3][lr] = wv.w;
    __syncthreads();
#pragma unroll
    for (int kk = 0; kk < 16; kk++) {
      float4 av = *reinterpret_cast<const float4*>(&As[kk][ty << 2]);
      float4 bv = *reinterpret_cast<const float4*>(&Bs[kk][tx << 2]);
      acc[0][0] += av.x * bv.x; acc[0][1] += av.x * bv.y; acc[0][2] += av.x * bv.z; acc[0][3] += av.x * bv.w;
      acc[1][0] += av.y * bv.x; acc[1][1] += av.y * bv.y; acc[1][2] += av.y * bv.z; acc[1][3] += av.y * bv.w;
      acc[2][0] += av.z * bv.x; acc[2][1] += av.z * bv.y; acc[2][2] += av.z * bv.z; acc[2][3] += av.z * bv.w;
      acc[3][0] += av.w * bv.x; acc[3][1] += av.w * bv.y; acc[3][2] += av.w * bv.z; acc[3][3] += av.w * bv.w;
    }
    __syncthreads();
  }

  int gn0 = n0 + (tx << 2);
#pragma unroll
  for (int i = 0; i < 4; i++) {
    int gm = m0 + (ty << 2) + i;
    if (gm >= M) break;
    float4 v = make_float4(acc[i][0], acc[i][1], acc[i][2], acc[i][3]);
    if constexpr (EPI == 1) {
      float4 bb = *(const float4*)(bias + gn0);
      float4 rr = *(const float4*)(resid + (size_t)gm * N + gn0);
      v.x += bb.x + rr.x; v.y += bb.y + rr.y; v.z += bb.z + rr.z; v.w += bb.w + rr.w;
      *(float4*)(outF + (size_t)gm * N + gn0) = v;
    } else {
      *(float4*)(outF + (size_t)gm * N + gn0) = v;
    }
  }
}

// ---------- pooled-token index decode ----------
__device__ __forceinline__ void decode_l(int l, int& gi, int& ph, int& pw,
                                         int& oh, int& ow, int& base) {
  if (l < 64)       { gi = 0; base = 0;   oh = 8; ow = 8; }
  else if (l < 100) { gi = 1; base = 64;  oh = 6; ow = 6; }
  else if (l < 125) { gi = 2; base = 100; oh = 5; ow = 5; }
  else              { gi = 3; base = 125; oh = 4; ow = 4; }
  int loc = l - base;
  ph = loc / ow; pw = loc % ow;
}

// ---------- pooling stage A: per bin-row-chunk partial sums ----------
__global__ __launch_bounds__(256) void pool_partial(const unsigned short* __restrict__ xn,
                                                    float* __restrict__ partial) {
  const int gid = blockIdx.x;
  const int b = gid / NUNIT, u = gid % NUNIT;
  int ow_, cr, ubase;
  if (u < 256)      { ubase = 0;   ow_ = 8; cr = 3; }
  else if (u < 400) { ubase = 256; ow_ = 6; cr = 4; }
  else if (u < 500) { ubase = 400; ow_ = 5; cr = 5; }
  else              { ubase = 500; ow_ = 4; cr = 6; }
  const int v = u - ubase;
  const int bin = v >> 2, chunk = v & 3;
  const int ph = bin / ow_, pw = bin % ow_;
  const int sh = (ph * HH) / ow_;
  const int sw = (pw * WW) / ow_, ew = ((pw + 1) * WW + ow_ - 1) / ow_;
  const int y0 = sh + chunk * cr, y1 = y0 + cr;

  const int tid = threadIdx.x;
  const int cg = tid & 63, pl = tid >> 6;
  const unsigned short* xb = xn + (size_t)b * NN * CC + (cg << 3);

  float acc[8] = {0.f, 0.f, 0.f, 0.f, 0.f, 0.f, 0.f, 0.f};
  for (int y = y0; y < y1; y++) {
    const unsigned short* xr = xb + (size_t)(y * WW) * CC;
    for (int xx = sw + pl; xx < ew; xx += 4) {
      int4 vv = *(const int4*)(xr + (size_t)xx * CC);
      unsigned ua = (unsigned)vv.x, ub = (unsigned)vv.y,
               uc = (unsigned)vv.z, ud = (unsigned)vv.w;
      acc[0] += bflo(ua); acc[1] += bfhi(ua);
      acc[2] += bflo(ub); acc[3] += bfhi(ub);
      acc[4] += bflo(uc); acc[5] += bfhi(uc);
      acc[6] += bflo(ud); acc[7] += bfhi(ud);
    }
  }
  __shared__ float red[4][64][8];
#pragma unroll
  for (int j = 0; j < 8; j++) red[pl][cg][j] = acc[j];
  __syncthreads();
  if (tid < 64) {
    float s[8];
#pragma unroll
    for (int j = 0; j < 8; j++)
      s[j] = red[0][tid][j] + red[1][tid][j] + red[2][tid][j] + red[3][tid][j];
    float* dst = partial + (size_t)gid * CC + (tid << 3);
    *(float4*)dst = make_float4(s[0], s[1], s[2], s[3]);
    *(float4*)(dst + 4) = make_float4(s[4], s[5], s[6], s[7]);
  }
}

// ---------- pooling stage B: sum 4 chunk-partials, apply 1/area ----------
__global__ __launch_bounds__(256) void pool_reduce(const float* __restrict__ partial,
                                                   float* __restrict__ pr) {
  const int bl = blockIdx.x;
  const int b = bl / LL, l = bl % LL;
  int gi, ph, pw, oh, ow, base; decode_l(l, gi, ph, pw, oh, ow, base);
  const int sh = (ph * HH) / oh, eh = ((ph + 1) * HH + oh - 1) / oh;
  const int sw = (pw * WW) / ow, ew = ((pw + 1) * WW + ow - 1) / ow;
  const float inv_area = 1.f / (float)((eh - sh) * (ew - sw));
  int u0;
  if (l < 64)       u0 = l * 4;
  else if (l < 100) u0 = 256 + (l - 64) * 4;
  else if (l < 125) u0 = 400 + (l - 100) * 4;
  else              u0 = 500 + (l - 125) * 4;
  const float* p0 = partial + ((size_t)(b * NUNIT + u0)) * CC;
  const int c = threadIdx.x << 1;
  float2 a0 = *(const float2*)(p0 + c);
  float2 a1 = *(const float2*)(p0 + CC + c);
  float2 a2 = *(const float2*)(p0 + 2 * CC + c);
  float2 a3 = *(const float2*)(p0 + 3 * CC + c);
  float2 r;
  r.x = (a0.x + a1.x + a2.x + a3.x) * inv_area;
  r.y = (a0.y + a1.y + a2.y + a3.y) * inv_area;
  *(float2*)(pr + ((size_t)(b * LL + l)) * CC + c) = r;
}

// ---------- pool += dwconv3x3(pool) + bias ----------
__global__ __launch_bounds__(256) void pool_dwconv(const float* __restrict__ pin,
                                                   const float* __restrict__ dw,
                                                   const float* __restrict__ db,
                                                   float* __restrict__ pout) {
  int bl = blockIdx.x;
  int b = bl / LL, l = bl % LL;
  int gi, ph, pw, oh, ow, base; decode_l(l, gi, ph, pw, oh, ow, base);
  for (int c = threadIdx.x; c < CC; c += 256) {
    float acc = db[gi * CC + c];
#pragma unroll
    for (int dy = -1; dy <= 1; dy++) {
      int y = ph + dy; if ((unsigned)y >= (unsigned)oh) continue;
#pragma unroll
      for (int dx = -1; dx <= 1; dx++) {
        int x = pw + dx; if ((unsigned)x >= (unsigned)ow) continue;
        acc += dw[((size_t)(gi * CC + c)) * 9 + (dy + 1) * 3 + (dx + 1)] *
               pin[((size_t)(b * LL) + base + y * ow + x) * CC + c];
      }
    }
    pout[((size_t)(b * LL + l)) * CC + c] =
        pin[((size_t)(b * LL + l)) * CC + c] + acc;
  }
}

// ---------- kv prep: f32 kv -> pre-swizzled bf16 K and V^T per (b,h) ----------
__global__ __launch_bounds__(256) void kvprep(const float* __restrict__ kvb,
                                              unsigned short* __restrict__ kpack,
                                              unsigned short* __restrict__ vtpack) {
  const int bh = blockIdx.x;
  const int b = bh >> 3, h = bh & 7;
  unsigned short* kd = kpack + (size_t)bh * 10240;
  unsigned short* vd = vtpack + (size_t)bh * 12288;
  for (int idx = threadIdx.x; idx < 1280; idx += 256) {
    const int row = idx >> 3, blk = idx & 7;
    int4 pk = make_int4(0, 0, 0, 0);
    if (row < LL) {
      const float* kp = kvb + ((size_t)(b * LL + row) << 10) + (h << 6) + (blk << 3);
      float4 v0 = *(const float4*)kp;
      float4 v1 = *(const float4*)(kp + 4);
      pk.x = (int)packbf(v0.x, v0.y); pk.y = (int)packbf(v0.z, v0.w);
      pk.z = (int)packbf(v1.x, v1.y); pk.w = (int)packbf(v1.z, v1.w);
    }
    *(int4*)(kd + row * 64 + ((blk ^ (row & 7)) << 3)) = pk;
    const int l = row, d0 = blk << 3, lb = l >> 3;
    unsigned short vv[8] = {0, 0, 0, 0, 0, 0, 0, 0};
    if (l < LL) {
      const float* vp = kvb + ((size_t)(b * LL + l) << 10) + 512 + (h << 6) + d0;
      float4 v0 = *(const float4*)vp;
      float4 v1 = *(const float4*)(vp + 4);
      vv[0] = f2bf(v0.x); vv[1] = f2bf(v0.y); vv[2] = f2bf(v0.z); vv[3] = f2bf(v0.w);
      vv[4] = f2bf(v1.x); vv[5] = f2bf(v1.y); vv[6] = f2bf(v1.z); vv[7] = f2bf(v1.w);
    }
#pragma unroll
    for (int j = 0; j < 8; j++) {
      const int d = d0 + j;
      vd[d * 192 + ((lb ^ (d & 7)) << 3) + (l & 7)] = vv[j];
    }
  }
}

// ---------- MFMA fused attention (pure gld_lds staging from pre-swizzled kv) ----------
__global__ __launch_bounds__(256) void attn_mfma(const unsigned short* __restrict__ q,
                                                 const unsigned short* __restrict__ kpack,
                                                 const unsigned short* __restrict__ vtpack,
                                                 unsigned short* __restrict__ out) {
  __shared__ __align__(16) unsigned short Ks[160 * 64];
  __shared__ __align__(16) unsigned short Vt[64 * 192];
  __shared__ __align__(16) unsigned short Pl[4 * 16 * 192];
  const int bh = blockIdx.x;
  const int b = bh >> 3;
  const int tid = threadIdx.x;
  const int w = tid >> 6, lane = tid & 63;

  const unsigned short* kg = kpack + (size_t)bh * 10240;
  const unsigned short* vg = vtpack + (size_t)bh * 12288;
#pragma unroll
  for (int p = 0; p < 5; p++)
    gld_lds16(kg + (p << 11) + (tid << 3), Ks + (p << 11) + (w << 9));
#pragma unroll
  for (int p = 0; p < 6; p++)
    gld_lds16(vg + (p << 11) + (tid << 3), Vt + (p << 11) + (w << 9));

  const int qrow = blockIdx.y * 64 + w * 16 + (lane & 15);
  const unsigned short* qp = q + ((size_t)(b * NN + qrow) << 9) + ((bh & 7) << 6) + ((lane >> 4) << 3);
  bf16x8 qf0 = *(const bf16x8*)qp;
  bf16x8 qf1 = *(const bf16x8*)(qp + 32);

  __syncthreads();

  f32x4 s[9];
  const int kb = lane >> 4;
  const int mycol = lane & 15;
#pragma unroll
  for (int lt = 0; lt < 9; lt++) {
    int lcol = lt * 16 + mycol;
    const unsigned short* kr = Ks + lcol * 64;
    bf16x8 k0 = *(const bf16x8*)(kr + ((kb ^ (lcol & 7)) << 3));
    bf16x8 k1 = *(const bf16x8*)(kr + (((kb + 4) ^ (lcol & 7)) << 3));
    f32x4 a = (f32x4){0.f, 0.f, 0.f, 0.f};
    a = __builtin_amdgcn_mfma_f32_16x16x32_bf16(qf0, k0, a, 0, 0, 0);
    a = __builtin_amdgcn_mfma_f32_16x16x32_bf16(qf1, k1, a, 0, 0, 0);
    s[lt] = a;
  }
#pragma unroll
  for (int lt = 0; lt < 9; lt++) {
#pragma unroll
    for (int j = 0; j < 4; j++) {
      float v = s[lt][j] * 0.125f;
      if (lt == 8 && mycol >= 13) v = -1e30f;
      s[lt][j] = v;
    }
  }
  float sm[4];
#pragma unroll
  for (int j = 0; j < 4; j++) {
    float m = s[0][j];
#pragma unroll
    for (int lt = 1; lt < 9; lt++) m = fmaxf(m, s[lt][j]);
#pragma unroll
    for (int off = 1; off < 16; off <<= 1) m = fmaxf(m, __shfl_xor(m, off, 64));
    float su = 0.f;
#pragma unroll
    for (int lt = 0; lt < 9; lt++) {
      float p = __expf(s[lt][j] - m);
      s[lt][j] = p;
      su += p;
    }
#pragma unroll
    for (int off = 1; off < 16; off <<= 1) su += __shfl_xor(su, off, 64);
    sm[j] = su;
  }

  unsigned short* Pw = Pl + w * (16 * 192);
#pragma unroll
  for (int lt = 0; lt < 9; lt++) {
#pragma unroll
    for (int j = 0; j < 4; j++) {
      int qr_ = (lane >> 4) * 4 + j;
      int lcol = lt * 16 + mycol;
      Pw[qr_ * 192 + (((lcol >> 3) ^ (qr_ & 7)) << 3) + (lcol & 7)] = f2bf(s[lt][j]);
    }
  }
#pragma unroll
  for (int j = 0; j < 4; j++) {
    int qr_ = mycol;
    int lcol = 144 + (lane >> 4) * 4 + j;
    Pw[qr_ * 192 + (((lcol >> 3) ^ (qr_ & 7)) << 3) + (lcol & 7)] = 0;
  }
  __syncthreads();

  f32x4 o[4];
#pragma unroll
  for (int dt = 0; dt < 4; dt++) o[dt] = (f32x4){0.f, 0.f, 0.f, 0.f};
#pragma unroll
  for (int lc = 0; lc < 5; lc++) {
    int lb = lc * 4 + (lane >> 4);
    bf16x8 pa = *(const bf16x8*)(Pw + mycol * 192 + ((lb ^ (mycol & 7)) << 3));
#pragma unroll
    for (int dt = 0; dt < 4; dt++) {
      int d = dt * 16 + mycol;
      bf16x8 vb = *(const bf16x8*)(Vt + d * 192 + ((lb ^ (d & 7)) << 3));
      o[dt] = __builtin_amdgcn_mfma_f32_16x16x32_bf16(pa, vb, o[dt], 0, 0, 0);
    }
  }

  float inv[4];
#pragma unroll
  for (int j = 0; j < 4; j++) inv[j] = 1.f / sm[j];
#pragma unroll
  for (int dt = 0; dt < 4; dt++) {
#pragma unroll
    for (int j = 0; j < 4; j++) {
      int qg = blockIdx.y * 64 + w * 16 + (lane >> 4) * 4 + j;
      out[((size_t)(b * NN + qg) << 9) + ((bh & 7) << 6) + dt * 16 + mycol] =
          f2bf(o[dt][j] * inv[j]);
    }
  }
}

// ---------- depthwise 3x3 sliding-window; grid (384, n_images) ----------
__device__ __forceinline__ void dw_ldcol(const unsigned short* __restrict__ img,
                                         int hh, int xx, int o0, float* __restrict__ f) {
  const bool xok = (unsigned)xx < (unsigned)WW;
#pragma unroll
  for (int r = 0; r < 3; r++) {
    const int y = hh - 1 + r;
    int4 v = make_int4(0, 0, 0, 0);
    if (xok && (unsigned)y < (unsigned)HH)
      v = *(const int4*)(img + ((size_t)(y * WW + xx) * HID) + o0);
    unsigned ua = (unsigned)v.x, ub = (unsigned)v.y,
             uc = (unsigned)v.z, ud = (unsigned)v.w;
    f[r * 8 + 0] = bflo(ua); f[r * 8 + 1] = bfhi(ua);
    f[r * 8 + 2] = bflo(ub); f[r * 8 + 3] = bfhi(ub);
    f[r * 8 + 4] = bflo(uc); f[r * 8 + 5] = bfhi(uc);
    f[r * 8 + 6] = bflo(ud); f[r * 8 + 7] = bfhi(ud);
  }
}

__device__ __forceinline__ void dw_emit(const float wr[9][8], const float bs[8],
                                        const float* __restrict__ A,
                                        const float* __restrict__ B,
                                        const float* __restrict__ C,
                                        unsigned short* __restrict__ t2,
                                        int hh, int xx, int o0) {
  float acc[8];
#pragma unroll
  for (int j = 0; j < 8; j++) acc[j] = bs[j];
#pragma unroll
  for (int r = 0; r < 3; r++) {
#pragma unroll
    for (int j = 0; j < 8; j++) {
      acc[j] += wr[r * 3 + 0][j] * A[r * 8 + j];
      acc[j] += wr[r * 3 + 1][j] * B[r * 8 + j];
      acc[j] += wr[r * 3 + 2][j] * C[r * 8 + j];
    }
  }
  int4 o;
  o.x = (int)packbf(hswish(acc[0]), hswish(acc[1]));
  o.y = (int)packbf(hswish(acc[2]), hswish(acc[3]));
  o.z = (int)packbf(hswish(acc[4]), hswish(acc[5]));
  o.w = (int)packbf(hswish(acc[6]), hswish(acc[7]));
  *(int4*)(t2 + ((size_t)(hh * WW + xx) * HID) + o0) = o;
}

__global__ __launch_bounds__(256) void dwconv_hid(const unsigned short* __restrict__ t1,
                                                  const float* __restrict__ wt,
                                                  const float* __restrict__ bias,
                                                  unsigned short* __restrict__ t2) {
  const int bx = blockIdx.x;            // 0..383
  const size_t ioff = (size_t)blockIdx.y * NN * HID;
  const unsigned short* t1i = t1 + ioff;
  unsigned short* t2i = t2 + ioff;
  const int hh = bx >> 2, quarter = bx & 3;
  const int x0 = quarter * 24;
  const int o0 = threadIdx.x << 3;

  float wr[9][8];
#pragma unroll
  for (int k = 0; k < 9; k++) {
    float4 w0 = *(const float4*)(wt + k * HID + o0);
    float4 w1 = *(const float4*)(wt + k * HID + o0 + 4);
    wr[k][0] = w0.x; wr[k][1] = w0.y; wr[k][2] = w0.z; wr[k][3] = w0.w;
    wr[k][4] = w1.x; wr[k][5] = w1.y; wr[k][6] = w1.z; wr[k][7] = w1.w;
  }
  float bs[8];
  {
    float4 b0 = *(const float4*)(bias + o0);
    float4 b1 = *(const float4*)(bias + o0 + 4);
    bs[0] = b0.x; bs[1] = b0.y; bs[2] = b0.z; bs[3] = b0.w;
    bs[4] = b1.x; bs[5] = b1.y; bs[6] = b1.z; bs[7] = b1.w;
  }

  float cm[24], cc[24], cn[24];
  dw_ldcol(t1i, hh, x0 - 1, o0, cm);
  dw_ldcol(t1i, hh, x0, o0, cc);
  for (int xx = x0; xx < x0 + 24; xx += 3) {
    dw_ldcol(t1i, hh, xx + 1, o0, cn);
    dw_emit(wr, bs, cm, cc, cn, t2i, hh, xx, o0);
    dw_ldcol(t1i, hh, xx + 2, o0, cm);
    dw_emit(wr, bs, cc, cn, cm, t2i, hh, xx + 1, o0);
    dw_ldcol(t1i, hh, xx + 3, o0, cc);
    dw_emit(wr, bs, cn, cm, cc, t2i, hh, xx + 2, o0);
  }
}

// ---------- launch ----------
extern "C" void kernel_launch(void* const* d_in, const int* in_sizes, int n_in,
                              void* d_out, int out_size, void* d_ws, size_t ws_size,
                              hipStream_t stream) {
  const float* x        = (const float*)d_in[0];
  const float* norm1_g  = (const float*)d_in[1];
  const float* norm1_b  = (const float*)d_in[2];
  const float* q_w      = (const float*)d_in[3];
  const float* kv_w     = (const float*)d_in[4];
  const float* anorm_g  = (const float*)d_in[5];
  const float* anorm_b  = (const float*)d_in[6];
  const float* proj_w   = (const float*)d_in[7];
  const float* proj_b   = (const float*)d_in[8];
  const float* dconv_w  = (const float*)d_in[9];
  const float* dconv_b  = (const float*)d_in[10];
  const float* norm2_g  = (const float*)d_in[11];
  const float* norm2_b  = (const float*)d_in[12];
  const float* fc1_w    = (const float*)d_in[13];
  const float* fc1_b    = (const float*)d_in[14];
  const float* conv_w   = (const float*)d_in[15];
  const float* conv_b   = (const float*)d_in[16];
  const float* fc2_w    = (const float*)d_in[17];
  const float* fc2_b    = (const float*)d_in[18];
  float* out = (float*)d_out;

  char* ws = (char*)d_ws;
  const size_t SZ_BIG = (size_t)BB * NN * CC * 2;          // 37,748,736
  unsigned short* bufA = (unsigned short*)(ws);
  unsigned short* bufB = (unsigned short*)(ws + SZ_BIG);
  unsigned short* bufC = (unsigned short*)(ws + 2 * SZ_BIG);
  // weights (persistent through launch)
  char* wbase = ws + 3 * SZ_BIG;
  unsigned short* qw16   = (unsigned short*)(wbase);                  // 524288 B
  unsigned short* pw16   = (unsigned short*)(wbase + 524288);         // 524288 B
  unsigned short* fc1w16 = (unsigned short*)(wbase + 1048576);        // 2097152 B
  unsigned short* fc2w16 = (unsigned short*)(wbase + 3145728);        // 2097152 B
  float* wt              = (float*)(wbase + 5242880);                 // 73728 B
  // kvb (dead after kvprep)
  float* kvb = (float*)(wbase + 5316608);                             // 2310144 B
  // scratch (phase-overlapped)
  char* sb = wbase + 7626752;
  float* pools_raw = (float*)(sb);                                    // 1155072 B
  float* pools_c   = (float*)(sb + 1155072);
  float* pools_n   = (float*)(sb + 2 * 1155072);
  float* pool_part = (float*)(sb + 3 * 1155072);                      // 4620288 B
  // kpack/vtpack written after pools are dead
  unsigned short* kpack  = (unsigned short*)(sb);                     // 655360 B
  unsigned short* vtpack = (unsigned short*)(sb + 655360);            // 786432 B
  // batched-IRB t2 (written after kvb/pools/kpack all dead)
  unsigned short* t2b = (unsigned short*)(wbase + 5316608);           // 75497472 B
  const size_t need_batched =
      3 * SZ_BIG + 5316608ull + (size_t)2 * NN * HID * 2;             // 194,060,288
  const bool batched = ws_size >= need_batched;

  const int ROWS = BB * NN;   // 36864

  w2bf<<<(262144 / 4 + 255) / 256, 256, 0, stream>>>(q_w, qw16, 262144 / 4);
  w2bf<<<(262144 / 4 + 255) / 256, 256, 0, stream>>>(proj_w, pw16, 262144 / 4);
  w2bf<<<(1048576 / 4 + 255) / 256, 256, 0, stream>>>(fc1_w, fc1w16, 1048576 / 4);
  w2bf<<<(1048576 / 4 + 255) / 256, 256, 0, stream>>>(fc2_w, fc2w16, 1048576 / 4);
  wtrans<<<(9 * HID + 255) / 256, 256, 0, stream>>>(conv_w, wt);

  ln_kernel<1><<<ROWS, 256, 0, stream>>>(x, norm1_g, norm1_b, bufA);
  gemm_mfma<3><<<dim3(ROWS / 128, CC / 128), 256, 0, stream>>>(
      bufA, qw16, nullptr, nullptr, nullptr, bufB, ROWS, CC, CC);
  pool_partial<<<BB * NUNIT, 256, 0, stream>>>(bufA, pool_part);
  pool_reduce<<<BB * LL, 256, 0, stream>>>(pool_part, pools_raw);
  pool_dwconv<<<BB * LL, 256, 0, stream>>>(pools_raw, dconv_w, dconv_b, pools_c);
  ln_kernel<0><<<BB * LL, 256, 0, stream>>>(pools_c, anorm_g, anorm_b, pools_n);
  gemm_xwt<float, 0><<<dim3((BB * LL + 63) / 64, (2 * CC) / 64), 256, 0, stream>>>(
      pools_n, kv_w, nullptr, nullptr, kvb, nullptr, BB * LL, 2 * CC, CC);
  kvprep<<<BB * NHEAD, 256, 0, stream>>>(kvb, kpack, vtpack);
  attn_mfma<<<dim3(BB * NHEAD, NN / 64), 256, 0, stream>>>(bufB, kpack, vtpack, bufC);
  gemm_mfma<1><<<dim3(ROWS / 128, CC / 128), 256, 0, stream>>>(
      bufC, pw16, proj_b, x, out, nullptr, ROWS, CC, CC);
  ln_kernel<1><<<ROWS, 256, 0, stream>>>(out, norm2_g, norm2_b, bufC);

  if (batched) {
    for (int g = 0; g < 2; g++) {
      const unsigned short* xn2g = bufC + (size_t)g * 2 * NN * CC;
      float* outg = out + (size_t)g * 2 * NN * CC;
      gemm_mfma<2><<<dim3(2 * NN / 128, HID / 128), 256, 0, stream>>>(
          xn2g, fc1w16, fc1_b, nullptr, nullptr, bufA, 2 * NN, HID, CC);
      dwconv_hid<<<dim3(384, 2), 256, 0, stream>>>(bufA, wt, conv_b, t2b);
      gemm_mfma<1><<<dim3(2 * NN / 128, CC / 128), 256, 0, stream>>>(
          t2b, fc2w16, fc2_b, outg, outg, nullptr, 2 * NN, CC, HID);
    }
  } else {
    for (int b = 0; b < BB; b++) {
      const unsigned short* xn2b = bufC + (size_t)b * NN * CC;
      gemm_mfma<2><<<dim3(NN / 128, HID / 128), 256, 0, stream>>>(
          xn2b, fc1w16, fc1_b, nullptr, nullptr, bufA, NN, HID, CC);
      dwconv_hid<<<dim3(384, 1), 256, 0, stream>>>(bufA, wt, conv_b, bufB);
      gemm_mfma<1><<<dim3(NN / 128, CC / 128), 256, 0, stream>>>(
          bufB, fc2w16, fc2_b, out + (size_t)b * NN * CC, out + (size_t)b * NN * CC,
          nullptr, NN, CC, HID);
    }
  }
}